// Round 3
// baseline (890.983 us; speedup 1.0000x reference)
//
#include <hip/hip_runtime.h>
#include <hip/hip_bf16.h>

// ---------------- Mamba2 block (B=2, L=2048, D_MODEL=2048, D_INNER=4096,
// NH=64, HP=64, DS=128, G=1, DCONV=4, CHUNK=256) ----------------
// Round 2: fix half-staged GEMM LDS tiles (q<2 -> q<4): uninit LDS cols 32..63
// were feeding MFMA -> NaN. Everything else unchanged from Round 1.

typedef __attribute__((ext_vector_type(8))) short bf16x8;
typedef __attribute__((ext_vector_type(4))) float f32x4;
typedef __attribute__((ext_vector_type(4))) float float4v;

#define MFMA(a,b,c) __builtin_amdgcn_mfma_f32_16x16x32_bf16((a),(b),(c),0,0,0)

__device__ __forceinline__ float bf2f(unsigned short u){
  union { unsigned int i; float f; } v; v.i = ((unsigned int)u) << 16; return v.f;
}
__device__ __forceinline__ unsigned short f2bf(float f){
  union { float f; unsigned int i; } v; v.f = f;
  unsigned int x = v.i;
  return (unsigned short)((x + 0x7fffu + ((x >> 16) & 1u)) >> 16);
}

// ---------- dt = softplus(u @ Wdt^T + dt_bias), f32 ----------
__global__ __launch_bounds__(256) void k_dt(const float* __restrict__ u,
                                            const float* __restrict__ Win,
                                            const float* __restrict__ dt_bias,
                                            float* __restrict__ dt_out){
  __shared__ float su[4][2048];
  int t = threadIdx.x, w = t >> 6, l = t & 63;
  int m0 = blockIdx.x * 4;
  #pragma unroll
  for (int q = 0; q < 8; q++){
    int id = t + q * 256;            // float4 index over 4*512
    int r = id >> 9, c4 = id & 511;
    ((float4v*)su[r])[c4] = ((const float4v*)(u + (size_t)(m0 + r) * 2048))[c4];
  }
  __syncthreads();
  int m = m0 + w;
  for (int h = 0; h < 64; h++){
    const float* wr = Win + (size_t)(8448 + h) * 2048;
    float acc = 0.f;
    #pragma unroll
    for (int i = 0; i < 8; i++){
      int k4 = l + i * 64;
      float4v a = ((const float4v*)su[w])[k4];
      float4v b = ((const float4v*)wr)[k4];
      acc += a.x * b.x + a.y * b.y + a.z * b.z + a.w * b.w;
    }
    #pragma unroll
    for (int off = 32; off >= 1; off >>= 1) acc += __shfl_xor(acc, off, 64);
    if (l == 0){
      float x = acc + dt_bias[h];
      dt_out[(size_t)m * 64 + h] = (x > 20.f) ? x : log1pf(expf(x));
    }
  }
}

// ---------- GEMM1: zxbc = u @ W_in^T (f32 in, on-the-fly bf16, split store) ----------
// M=4096, N=8448 (skip dt cols), K=2048. Grid (66, 32).
__global__ __launch_bounds__(256) void k_gemm1(const float* __restrict__ A,
                                               const float* __restrict__ B,
                                               unsigned short* __restrict__ zbuf,
                                               unsigned short* __restrict__ xbc){
  __shared__ unsigned short sA[128][72];
  __shared__ unsigned short sB[128][72];
  const int K = 2048;
  int t = threadIdx.x, w = t >> 6, l = t & 63;
  int mbase = blockIdx.y * 128, nbase = blockIdx.x * 128;
  int wr = (w >> 1) * 64, wc = (w & 1) * 64;
  f32x4 acc[4][4];
  #pragma unroll
  for (int i = 0; i < 4; i++)
    #pragma unroll
    for (int j = 0; j < 4; j++) acc[i][j] = (f32x4){0.f,0.f,0.f,0.f};

  for (int kb = 0; kb < K; kb += 64){
    #pragma unroll
    for (int q = 0; q < 4; q++){
      int id = t + q * 256;          // 1024 chunks of 8 elems (full 128x64 tile)
      int r = id >> 3, g = id & 7;
      const float* ap = A + (size_t)(mbase + r) * K + kb + g * 8;
      const float* bp = B + (size_t)(nbase + r) * K + kb + g * 8;
      float4v a0 = *(const float4v*)ap, a1 = *(const float4v*)(ap + 4);
      float4v b0 = *(const float4v*)bp, b1 = *(const float4v*)(bp + 4);
      bf16x8 av, bv;
      av[0]=(short)f2bf(a0.x); av[1]=(short)f2bf(a0.y); av[2]=(short)f2bf(a0.z); av[3]=(short)f2bf(a0.w);
      av[4]=(short)f2bf(a1.x); av[5]=(short)f2bf(a1.y); av[6]=(short)f2bf(a1.z); av[7]=(short)f2bf(a1.w);
      bv[0]=(short)f2bf(b0.x); bv[1]=(short)f2bf(b0.y); bv[2]=(short)f2bf(b0.z); bv[3]=(short)f2bf(b0.w);
      bv[4]=(short)f2bf(b1.x); bv[5]=(short)f2bf(b1.y); bv[6]=(short)f2bf(b1.z); bv[7]=(short)f2bf(b1.w);
      *(bf16x8*)&sA[r][g * 8] = av;
      *(bf16x8*)&sB[r][g * 8] = bv;
    }
    __syncthreads();
    #pragma unroll
    for (int ks = 0; ks < 64; ks += 32){
      int kk = ks + ((l >> 4) << 3);
      bf16x8 af[4], bfv[4];
      #pragma unroll
      for (int it = 0; it < 4; it++) af[it]  = *(const bf16x8*)&sA[wr + it * 16 + (l & 15)][kk];
      #pragma unroll
      for (int nt = 0; nt < 4; nt++) bfv[nt] = *(const bf16x8*)&sB[wc + nt * 16 + (l & 15)][kk];
      #pragma unroll
      for (int it = 0; it < 4; it++)
        #pragma unroll
        for (int nt = 0; nt < 4; nt++)
          acc[it][nt] = MFMA(af[it], bfv[nt], acc[it][nt]);
    }
    __syncthreads();
  }
  #pragma unroll
  for (int it = 0; it < 4; it++)
    #pragma unroll
    for (int nt = 0; nt < 4; nt++)
      #pragma unroll
      for (int r = 0; r < 4; r++){
        int m = mbase + wr + it * 16 + ((l >> 4) << 2) + r;
        int n = nbase + wc + nt * 16 + (l & 15);
        unsigned short v = f2bf(acc[it][nt][r]);
        if (n < 4096) zbuf[(size_t)m * 4096 + n] = v;
        else          xbc[(size_t)m * 4352 + (n - 4096)] = v;
      }
}

// ---------- GEMM2: out = yn @ W_out^T (A bf16, B f32 on-the-fly, f32 out) ----------
// M=4096, N=2048, K=4096. Grid (16, 32).
__global__ __launch_bounds__(256) void k_gemm2(const unsigned short* __restrict__ A,
                                               const float* __restrict__ B,
                                               float* __restrict__ C){
  __shared__ unsigned short sA[128][72];
  __shared__ unsigned short sB[128][72];
  const int K = 4096, N = 2048;
  int t = threadIdx.x, w = t >> 6, l = t & 63;
  int mbase = blockIdx.y * 128, nbase = blockIdx.x * 128;
  int wr = (w >> 1) * 64, wc = (w & 1) * 64;
  f32x4 acc[4][4];
  #pragma unroll
  for (int i = 0; i < 4; i++)
    #pragma unroll
    for (int j = 0; j < 4; j++) acc[i][j] = (f32x4){0.f,0.f,0.f,0.f};

  for (int kb = 0; kb < K; kb += 64){
    #pragma unroll
    for (int q = 0; q < 4; q++){
      int id = t + q * 256;          // 1024 chunks of 8 elems (full 128x64 tile)
      int r = id >> 3, g = id & 7;
      bf16x8 av = *(const bf16x8*)(A + (size_t)(mbase + r) * K + kb + g * 8);
      *(bf16x8*)&sA[r][g * 8] = av;
      const float* bp = B + (size_t)(nbase + r) * K + kb + g * 8;
      float4v b0 = *(const float4v*)bp, b1 = *(const float4v*)(bp + 4);
      bf16x8 bv;
      bv[0]=(short)f2bf(b0.x); bv[1]=(short)f2bf(b0.y); bv[2]=(short)f2bf(b0.z); bv[3]=(short)f2bf(b0.w);
      bv[4]=(short)f2bf(b1.x); bv[5]=(short)f2bf(b1.y); bv[6]=(short)f2bf(b1.z); bv[7]=(short)f2bf(b1.w);
      *(bf16x8*)&sB[r][g * 8] = bv;
    }
    __syncthreads();
    #pragma unroll
    for (int ks = 0; ks < 64; ks += 32){
      int kk = ks + ((l >> 4) << 3);
      bf16x8 af[4], bfv[4];
      #pragma unroll
      for (int it = 0; it < 4; it++) af[it]  = *(const bf16x8*)&sA[wr + it * 16 + (l & 15)][kk];
      #pragma unroll
      for (int nt = 0; nt < 4; nt++) bfv[nt] = *(const bf16x8*)&sB[wc + nt * 16 + (l & 15)][kk];
      #pragma unroll
      for (int it = 0; it < 4; it++)
        #pragma unroll
        for (int nt = 0; nt < 4; nt++)
          acc[it][nt] = MFMA(af[it], bfv[nt], acc[it][nt]);
    }
    __syncthreads();
  }
  #pragma unroll
  for (int it = 0; it < 4; it++)
    #pragma unroll
    for (int nt = 0; nt < 4; nt++)
      #pragma unroll
      for (int r = 0; r < 4; r++){
        int m = mbase + wr + it * 16 + ((l >> 4) << 2) + r;
        int n = nbase + wc + nt * 16 + (l & 15);
        C[(size_t)m * N + n] = acc[it][nt][r];
      }
}

// ---------- causal depthwise conv (DCONV=4) + bias + silu ----------
__global__ __launch_bounds__(256) void k_conv(const unsigned short* __restrict__ xbc,
                                              const float* __restrict__ cw,
                                              const float* __restrict__ cb,
                                              unsigned short* __restrict__ xc){
  int idx = blockIdx.x * 256 + threadIdx.x;   // over 4096*544
  int tok = idx / 544;
  int ch0 = (idx - tok * 544) * 8;
  int l = tok & 2047;
  float acc[8];
  #pragma unroll
  for (int e = 0; e < 8; e++) acc[e] = cb[ch0 + e];
  #pragma unroll
  for (int d = 0; d < 4; d++){
    int ll = l - 3 + d;
    if (ll < 0) continue;
    bf16x8 v = *(const bf16x8*)(xbc + (size_t)(tok - 3 + d) * 4352 + ch0);
    #pragma unroll
    for (int e = 0; e < 8; e++)
      acc[e] += bf2f((unsigned short)v[e]) * cw[(ch0 + e) * 4 + d];
  }
  bf16x8 ov;
  #pragma unroll
  for (int e = 0; e < 8; e++){
    float a = acc[e];
    float s = a / (1.f + expf(-a));
    ov[e] = (short)f2bf(s);
  }
  *(bf16x8*)(xc + (size_t)tok * 4352 + ch0) = ov;
}

// inclusive prefix sum of 256 floats in LDS (caller: barrier before; ends with barrier)
__device__ __forceinline__ void cumsum256(float* s, int t){
  for (int off = 1; off < 256; off <<= 1){
    float v = (t >= off) ? s[t - off] : 0.f;
    __syncthreads();
    s[t] += v;
    __syncthreads();
  }
}

// ---------- per-(b,c,h) chunk states: states[p][n] = sum_j w[j] B[j][n] x[j][p] ----------
// j processed in two halves of 128 to stay under 64KB LDS.
__global__ __launch_bounds__(256) void k_states(const unsigned short* __restrict__ xc,
                                                const float* __restrict__ dtw,
                                                const float* __restrict__ A_log,
                                                float* __restrict__ states,
                                                float* __restrict__ cdec){
  __shared__ unsigned short sBT[128][136];   // B^T: [n][j_local]
  __shared__ unsigned short swxT[64][136];   // (w*x)^T: [p][j_local]
  __shared__ float sdA[256];
  __shared__ float sdt[256];
  int t = threadIdx.x, w = t >> 6, l = t & 63;
  int h = blockIdx.x & 63, c = (blockIdx.x >> 6) & 7, b = blockIdx.x >> 9;
  int tok0 = b * 2048 + c * 256;

  float dtv = dtw[(size_t)(tok0 + t) * 64 + h];
  float Ah = -expf(A_log[h]);
  sdA[t] = dtv * Ah;
  sdt[t] = dtv;
  __syncthreads();
  cumsum256(sdA, t);
  float dA_end = sdA[255];
  if (t == 0) cdec[blockIdx.x] = expf(dA_end);

  f32x4 acc[4][2];
  #pragma unroll
  for (int i = 0; i < 4; i++){ acc[i][0] = (f32x4){0,0,0,0}; acc[i][1] = (f32x4){0,0,0,0}; }

  for (int jh = 0; jh < 2; jh++){
    // stage B^T half
    #pragma unroll
    for (int q = 0; q < 8; q++){
      int id = t + q * 256;          // 2048 chunks of 8
      int jl = id >> 4, g = id & 15;
      int j = jh * 128 + jl;
      bf16x8 v = *(const bf16x8*)(xc + (size_t)(tok0 + j) * 4352 + 4096 + g * 8);
      #pragma unroll
      for (int e = 0; e < 8; e++) sBT[g * 8 + e][jl] = (unsigned short)v[e];
    }
    // stage (w*x)^T half
    #pragma unroll
    for (int q = 0; q < 4; q++){
      int id = t + q * 256;          // 1024 chunks of 8
      int jl = id >> 3, g = id & 7;
      int j = jh * 128 + jl;
      float wj = expf(dA_end - sdA[j]) * sdt[j];
      bf16x8 v = *(const bf16x8*)(xc + (size_t)(tok0 + j) * 4352 + h * 64 + g * 8);
      #pragma unroll
      for (int e = 0; e < 8; e++) swxT[g * 8 + e][jl] = f2bf(bf2f((unsigned short)v[e]) * wj);
    }
    __syncthreads();
    #pragma unroll
    for (int ks = 0; ks < 4; ks++){
      int kk = ks * 32 + ((l >> 4) << 3);
      bf16x8 afr[4], bfr[2];
      #pragma unroll
      for (int pt = 0; pt < 4; pt++) afr[pt] = *(const bf16x8*)&swxT[pt * 16 + (l & 15)][kk];
      #pragma unroll
      for (int nt = 0; nt < 2; nt++) bfr[nt] = *(const bf16x8*)&sBT[(w * 2 + nt) * 16 + (l & 15)][kk];
      #pragma unroll
      for (int pt = 0; pt < 4; pt++)
        #pragma unroll
        for (int nt = 0; nt < 2; nt++)
          acc[pt][nt] = MFMA(afr[pt], bfr[nt], acc[pt][nt]);
    }
    __syncthreads();
  }
  float* sp = states + (size_t)blockIdx.x * 8192;
  #pragma unroll
  for (int pt = 0; pt < 4; pt++)
    #pragma unroll
    for (int nt = 0; nt < 2; nt++)
      #pragma unroll
      for (int r = 0; r < 4; r++){
        int p = pt * 16 + ((l >> 4) << 2) + r;
        int n = (w * 2 + nt) * 16 + (l & 15);
        sp[p * 128 + n] = acc[pt][nt][r];
      }
}

// ---------- sequential scan over 8 chunks per (b,h) ----------
__global__ __launch_bounds__(256) void k_scan(const float* __restrict__ states,
                                              const float* __restrict__ cdec,
                                              unsigned short* __restrict__ hprev){
  int b = blockIdx.x >> 6, h = blockIdx.x & 63;
  int t = threadIdx.x;
  float carry[32];
  #pragma unroll
  for (int i = 0; i < 32; i++) carry[i] = 0.f;
  for (int c = 0; c < 8; c++){
    int bch = (b * 8 + c) * 64 + h;
    size_t base = (size_t)bch * 8192;
    float d = cdec[bch];
    #pragma unroll
    for (int i = 0; i < 32; i++){
      int e = t + i * 256;
      hprev[base + e] = f2bf(carry[i]);
      carry[i] = carry[i] * d + states[base + e];
    }
  }
}

// ---------- per-(b,c,h): y = (scores@x) + (C*expf)@h_prev^T + Dp*x ----------
__global__ __launch_bounds__(256) void k_y(const unsigned short* __restrict__ xc,
                                           const float* __restrict__ dtw,
                                           const float* __restrict__ A_log,
                                           const unsigned short* __restrict__ hprev,
                                           const float* __restrict__ Dp,
                                           unsigned short* __restrict__ y){
  __shared__ unsigned short sxT[64][264];     // x^T: [p][j]
  __shared__ unsigned short sS[4][64][40];    // per-wave scores tile (64 i x 32 j)
  __shared__ float sdA[256];
  __shared__ float sdt[256];
  int t = threadIdx.x, w = t >> 6, l = t & 63;
  int h = blockIdx.x & 63, c = (blockIdx.x >> 6) & 7, b = blockIdx.x >> 9;
  int tok0 = b * 2048 + c * 256;
  int ib = w * 64;                            // wave's i-stripe base

  float dtv = dtw[(size_t)(tok0 + t) * 64 + h];
  float Ah = -expf(A_log[h]);
  sdA[t] = dtv * Ah;
  sdt[t] = dtv;
  __syncthreads();
  cumsum256(sdA, t);

  // stage x^T
  #pragma unroll
  for (int q = 0; q < 8; q++){
    int id = t + q * 256;
    int j = id >> 3, g = id & 7;
    bf16x8 v = *(const bf16x8*)(xc + (size_t)(tok0 + j) * 4352 + h * 64 + g * 8);
    #pragma unroll
    for (int e = 0; e < 8; e++) sxT[g * 8 + e][j] = (unsigned short)v[e];
  }
  __syncthreads();

  // C fragments in registers (A-operand: row i = l&15, k n = 8*(l>>4)+e)
  bf16x8 cfr[4][4];
  #pragma unroll
  for (int it = 0; it < 4; it++)
    #pragma unroll
    for (int kn = 0; kn < 4; kn++){
      int i = ib + it * 16 + (l & 15);
      int n = kn * 32 + ((l >> 4) << 3);
      cfr[it][kn] = *(const bf16x8*)(xc + (size_t)(tok0 + i) * 4352 + 4224 + n);
    }

  f32x4 acc[4][4];
  #pragma unroll
  for (int i = 0; i < 4; i++)
    #pragma unroll
    for (int j = 0; j < 4; j++) acc[i][j] = (f32x4){0,0,0,0};

  for (int jt = 0; jt < 8; jt++){
    // CB = C @ B^T for this 64x32 j-tile
    f32x4 cb[4][2];
    #pragma unroll
    for (int i = 0; i < 4; i++){ cb[i][0] = (f32x4){0,0,0,0}; cb[i][1] = (f32x4){0,0,0,0}; }
    #pragma unroll
    for (int kn = 0; kn < 4; kn++){
      bf16x8 bfr[2];
      #pragma unroll
      for (int js = 0; js < 2; js++){
        int j = jt * 32 + js * 16 + (l & 15);
        int n = kn * 32 + ((l >> 4) << 3);
        bfr[js] = *(const bf16x8*)(xc + (size_t)(tok0 + j) * 4352 + 4096 + n);
      }
      #pragma unroll
      for (int it = 0; it < 4; it++)
        #pragma unroll
        for (int js = 0; js < 2; js++)
          cb[it][js] = MFMA(cfr[it][kn], bfr[js], cb[it][js]);
    }
    // masked scores -> bf16 in wave-private LDS (relayout D->A)
    #pragma unroll
    for (int it = 0; it < 4; it++)
      #pragma unroll
      for (int js = 0; js < 2; js++)
        #pragma unroll
        for (int r = 0; r < 4; r++){
          int il = it * 16 + ((l >> 4) << 2) + r;       // local i (0..63)
          int i = ib + il;
          int j = jt * 32 + js * 16 + (l & 15);
          float v = (i >= j) ? cb[it][js][r] * expf(sdA[i] - sdA[j]) * sdt[j] : 0.f;
          sS[w][il][js * 16 + (l & 15)] = f2bf(v);
        }
    // y_diag += scores @ x   (wave-private LDS; same-wave DS ordering)
    int kk = ((l >> 4) << 3);
    bf16x8 sfr[4], xfr[4];
    #pragma unroll
    for (int it = 0; it < 4; it++) sfr[it] = *(const bf16x8*)&sS[w][it * 16 + (l & 15)][kk];
    #pragma unroll
    for (int pt = 0; pt < 4; pt++) xfr[pt] = *(const bf16x8*)&sxT[pt * 16 + (l & 15)][jt * 32 + kk];
    #pragma unroll
    for (int it = 0; it < 4; it++)
      #pragma unroll
      for (int pt = 0; pt < 4; pt++)
        acc[it][pt] = MFMA(sfr[it], xfr[pt], acc[it][pt]);
  }

  // y_off += (C * exp(dA_cs[i])) @ h_prev^T
  const unsigned short* hp = hprev + (size_t)blockIdx.x * 8192;
  float esc[4];
  #pragma unroll
  for (int it = 0; it < 4; it++) esc[it] = expf(sdA[ib + it * 16 + (l & 15)]);
  #pragma unroll
  for (int kn = 0; kn < 4; kn++){
    bf16x8 hfr[4];
    #pragma unroll
    for (int pt = 0; pt < 4; pt++){
      int p = pt * 16 + (l & 15);
      int n = kn * 32 + ((l >> 4) << 3);
      hfr[pt] = *(const bf16x8*)(hp + p * 128 + n);
    }
    #pragma unroll
    for (int it = 0; it < 4; it++){
      bf16x8 afv;
      #pragma unroll
      for (int e = 0; e < 8; e++)
        afv[e] = (short)f2bf(bf2f((unsigned short)cfr[it][kn][e]) * esc[it]);
      #pragma unroll
      for (int pt = 0; pt < 4; pt++)
        acc[it][pt] = MFMA(afv, hfr[pt], acc[it][pt]);
    }
  }

  // epilogue: + Dp*x, store y[tok][h*64+p]
  float dph = Dp[h];
  #pragma unroll
  for (int it = 0; it < 4; it++)
    #pragma unroll
    for (int pt = 0; pt < 4; pt++)
      #pragma unroll
      for (int r = 0; r < 4; r++){
        int i = ib + it * 16 + ((l >> 4) << 2) + r;
        int p = pt * 16 + (l & 15);
        float xv = bf2f(sxT[p][i]);
        float v = acc[it][pt][r] + dph * xv;
        y[(size_t)(tok0 + i) * 4096 + h * 64 + p] = f2bf(v);
      }
}

// ---------- gate with silu(z), RMS-norm, * norm_w -> bf16 ----------
__global__ __launch_bounds__(256) void k_norm(const unsigned short* __restrict__ y,
                                              const unsigned short* __restrict__ zbuf,
                                              const float* __restrict__ norm_w,
                                              unsigned short* __restrict__ yn){
  int tok = blockIdx.x, t = threadIdx.x, w = t >> 6, l = t & 63;
  float vals[16];
  float ss = 0.f;
  #pragma unroll
  for (int q = 0; q < 2; q++){
    int col = q * 2048 + t * 8;
    bf16x8 yv = *(const bf16x8*)(y    + (size_t)tok * 4096 + col);
    bf16x8 zv = *(const bf16x8*)(zbuf + (size_t)tok * 4096 + col);
    #pragma unroll
    for (int e = 0; e < 8; e++){
      float yy = bf2f((unsigned short)yv[e]);
      float zz = bf2f((unsigned short)zv[e]);
      float g = yy * (zz / (1.f + expf(-zz)));
      vals[q * 8 + e] = g;
      ss += g * g;
    }
  }
  #pragma unroll
  for (int off = 32; off >= 1; off >>= 1) ss += __shfl_xor(ss, off, 64);
  __shared__ float red[4];
  if (l == 0) red[w] = ss;
  __syncthreads();
  float total = red[0] + red[1] + red[2] + red[3];
  float scale = rsqrtf(total * (1.f / 4096.f) + 1e-5f);
  #pragma unroll
  for (int q = 0; q < 2; q++){
    int col = q * 2048 + t * 8;
    bf16x8 ov;
    #pragma unroll
    for (int e = 0; e < 8; e++) ov[e] = (short)f2bf(vals[q * 8 + e] * scale * norm_w[col + e]);
    *(bf16x8*)(yn + (size_t)tok * 4096 + col) = ov;
  }
}

extern "C" void kernel_launch(void* const* d_in, const int* in_sizes, int n_in,
                              void* d_out, int out_size, void* d_ws, size_t ws_size,
                              hipStream_t stream) {
  const float* u       = (const float*)d_in[0];
  const float* W_in    = (const float*)d_in[1];
  const float* conv_w  = (const float*)d_in[2];
  const float* conv_b  = (const float*)d_in[3];
  const float* dt_bias = (const float*)d_in[4];
  const float* A_log   = (const float*)d_in[5];
  const float* Dp      = (const float*)d_in[6];
  const float* norm_w  = (const float*)d_in[7];
  const float* W_out   = (const float*)d_in[8];

  char* ws = (char*)d_ws;
  size_t off = 0;
  auto nxt = [&](size_t bytes) -> char* {
    char* r = ws + off;
    off += (bytes + 255) & ~(size_t)255;
    return r;
  };
  // R_Z: z (bf16) lives until k_norm
  unsigned short* zbuf = (unsigned short*)nxt(4096ull * 4096 * 2);
  // R_X: xbc (bf16, 35.7MB) -> states (f32, 33.6MB) -> ybuf (bf16, 33.6MB)
  char* RX = nxt(4096ull * 4352 * 2);
  // R_C: xc (bf16, 35.7MB) -> ynbuf (bf16, 33.6MB)
  char* RC = nxt(4096ull * 4352 * 2);
  unsigned short* hprev = (unsigned short*)nxt(1024ull * 8192 * 2);
  float*          dtw   = (float*)nxt(4096ull * 64 * 4);
  float*          cdec  = (float*)nxt(1024ull * 4);
  size_t need = off;
  (void)in_sizes; (void)n_in; (void)out_size;
  if (ws_size < need) return;   // graceful: leaves d_out zeroed (clean failure, diagnostic)

  unsigned short* xbc    = (unsigned short*)RX;
  float*          states = (float*)RX;
  unsigned short* ybuf   = (unsigned short*)RX;
  unsigned short* xc     = (unsigned short*)RC;
  unsigned short* ynbuf  = (unsigned short*)RC;

  k_dt<<<1024, 256, 0, stream>>>(u, W_in, dt_bias, dtw);
  k_gemm1<<<dim3(66, 32), 256, 0, stream>>>(u, W_in, zbuf, xbc);
  k_conv<<<8704, 256, 0, stream>>>(xbc, conv_w, conv_b, xc);
  k_states<<<1024, 256, 0, stream>>>(xc, dtw, A_log, states, cdec);
  k_scan<<<128, 256, 0, stream>>>(states, cdec, hprev);
  k_y<<<1024, 256, 0, stream>>>(xc, dtw, A_log, hprev, Dp, ybuf);
  k_norm<<<4096, 256, 0, stream>>>(ybuf, zbuf, norm_w, ynbuf);
  k_gemm2<<<dim3(16, 32), 256, 0, stream>>>(ynbuf, W_out, (float*)d_out);
}

// Round 4
// 742.085 us; speedup vs baseline: 1.2006x; 1.2006x over previous
//
#include <hip/hip_runtime.h>
#include <hip/hip_bf16.h>

// ---------------- Mamba2 block (B=2, L=2048, D_MODEL=2048, D_INNER=4096,
// NH=64, HP=64, DS=128, G=1, DCONV=4, CHUNK=256) ----------------
// Round 3: m97-structure GEMMs (bf16 operands in memory + global_load_lds
// width-16 staging + XCD swizzle). Pre-cast u/W_in/W_out to bf16 into dead
// workspace windows (no net ws growth). SSM kernels unchanged.

typedef __attribute__((ext_vector_type(8))) short bf16x8;
typedef __attribute__((ext_vector_type(4))) float f32x4;
typedef __attribute__((ext_vector_type(4))) float float4v;

#define MFMA(a,b,c) __builtin_amdgcn_mfma_f32_16x16x32_bf16((a),(b),(c),0,0,0)

// async global->LDS, 16B per lane (wave-uniform LDS base + lane*16 semantics;
// lane-consecutive lds pointers required -> linear LDS layout)
#define GLOAD_LDS16(gp, lp) \
  __builtin_amdgcn_global_load_lds((const __attribute__((address_space(1))) void*)(gp), \
                                   (__attribute__((address_space(3))) void*)(lp), 16, 0, 0)

__device__ __forceinline__ float bf2f(unsigned short u){
  union { unsigned int i; float f; } v; v.i = ((unsigned int)u) << 16; return v.f;
}
__device__ __forceinline__ unsigned short f2bf(float f){
  union { float f; unsigned int i; } v; v.f = f;
  unsigned int x = v.i;
  return (unsigned short)((x + 0x7fffu + ((x >> 16) & 1u)) >> 16);
}

// ---------- f32 -> bf16 (vectorized cast) ----------
__global__ __launch_bounds__(256) void k_f2bf(const float* __restrict__ in,
                                              unsigned short* __restrict__ out, int n){
  int i = (blockIdx.x * 256 + threadIdx.x) * 4;
  if (i >= n) return;
  float4v v = *(const float4v*)(in + i);
  union { unsigned short u[4]; unsigned long long ll; } o;
  o.u[0] = f2bf(v.x); o.u[1] = f2bf(v.y); o.u[2] = f2bf(v.z); o.u[3] = f2bf(v.w);
  *(unsigned long long*)(out + i) = o.ll;
}

// ---------- dt = softplus(u @ Wdt^T + dt_bias), f32 ----------
__global__ __launch_bounds__(256) void k_dt(const float* __restrict__ u,
                                            const float* __restrict__ Win,
                                            const float* __restrict__ dt_bias,
                                            float* __restrict__ dt_out){
  __shared__ float su[4][2048];
  int t = threadIdx.x, w = t >> 6, l = t & 63;
  int m0 = blockIdx.x * 4;
  #pragma unroll
  for (int q = 0; q < 8; q++){
    int id = t + q * 256;            // float4 index over 4*512
    int r = id >> 9, c4 = id & 511;
    ((float4v*)su[r])[c4] = ((const float4v*)(u + (size_t)(m0 + r) * 2048))[c4];
  }
  __syncthreads();
  int m = m0 + w;
  for (int h = 0; h < 64; h++){
    const float* wr = Win + (size_t)(8448 + h) * 2048;
    float acc = 0.f;
    #pragma unroll
    for (int i = 0; i < 8; i++){
      int k4 = l + i * 64;
      float4v a = ((const float4v*)su[w])[k4];
      float4v b = ((const float4v*)wr)[k4];
      acc += a.x * b.x + a.y * b.y + a.z * b.z + a.w * b.w;
    }
    #pragma unroll
    for (int off = 32; off >= 1; off >>= 1) acc += __shfl_xor(acc, off, 64);
    if (l == 0){
      float x = acc + dt_bias[h];
      dt_out[(size_t)m * 64 + h] = (x > 20.f) ? x : log1pf(expf(x));
    }
  }
}

// ---------- m97-structure bf16 NT GEMM: C[m][n] = sum_k A[m][k]*B[n][k] ----------
// 128x128 tile, BK=64, linear LDS, global_load_lds dwordx4 staging, XCD swizzle.
// Caller guarantees M%128==0, N%128==0, K%64==0, grid divisible by 8.
// MODE 0: plain f32 out (stride N). MODE 1: bf16 split store (z / xbc).
template<int MODE>
__global__ __launch_bounds__(256) void k_gemm_bf(const unsigned short* __restrict__ A,
                                                 const unsigned short* __restrict__ B,
                                                 void* __restrict__ out0,
                                                 void* __restrict__ out1,
                                                 int M, int N, int K){
  __shared__ unsigned short sA[128 * 64];
  __shared__ unsigned short sB[128 * 64];
  int t = threadIdx.x, w = t >> 6, l = t & 63;
  // bijective XCD swizzle: dispatch slot bid computes tile sbid
  int nbx = gridDim.x;
  int bid = blockIdx.y * nbx + blockIdx.x;
  int cpx = (nbx * gridDim.y) >> 3;
  int sbid = (bid & 7) * cpx + (bid >> 3);
  int bx = sbid % nbx, by = sbid / nbx;
  int mbase = by * 128, nbase = bx * 128;
  int wr = (w >> 1) * 64, wc = (w & 1) * 64;

  f32x4 acc[4][4];
  #pragma unroll
  for (int i = 0; i < 4; i++)
    #pragma unroll
    for (int j = 0; j < 4; j++) acc[i][j] = (f32x4){0.f,0.f,0.f,0.f};

  const unsigned short* Ab = A + (size_t)mbase * K;
  const unsigned short* Bb = B + (size_t)nbase * K;
  int r0 = t >> 3, g0 = (t & 7) * 8;             // this thread's chunk (row, col)
  for (int kb = 0; kb < K; kb += 64){
    #pragma unroll
    for (int q = 0; q < 4; q++){
      int c = t + q * 256;                        // chunk 0..1023 (16B each)
      int r = r0 + q * 32;
      GLOAD_LDS16(Ab + (size_t)r * K + kb + g0, &sA[c * 8]);
      GLOAD_LDS16(Bb + (size_t)r * K + kb + g0, &sB[c * 8]);
    }
    __syncthreads();
    #pragma unroll
    for (int ks = 0; ks < 64; ks += 32){
      int kk = ks + ((l >> 4) << 3);
      bf16x8 af[4], bfv[4];
      #pragma unroll
      for (int it = 0; it < 4; it++) af[it]  = *(const bf16x8*)&sA[(wr + it * 16 + (l & 15)) * 64 + kk];
      #pragma unroll
      for (int nt = 0; nt < 4; nt++) bfv[nt] = *(const bf16x8*)&sB[(wc + nt * 16 + (l & 15)) * 64 + kk];
      #pragma unroll
      for (int it = 0; it < 4; it++)
        #pragma unroll
        for (int nt = 0; nt < 4; nt++)
          acc[it][nt] = MFMA(af[it], bfv[nt], acc[it][nt]);
    }
    __syncthreads();
  }
  #pragma unroll
  for (int it = 0; it < 4; it++)
    #pragma unroll
    for (int nt = 0; nt < 4; nt++)
      #pragma unroll
      for (int r = 0; r < 4; r++){
        int m = mbase + wr + it * 16 + ((l >> 4) << 2) + r;
        int n = nbase + wc + nt * 16 + (l & 15);
        float v = acc[it][nt][r];
        if (MODE == 0){
          ((float*)out0)[(size_t)m * N + n] = v;
        } else {
          unsigned short bv = f2bf(v);
          if (n < 4096) ((unsigned short*)out0)[(size_t)m * 4096 + n] = bv;
          else          ((unsigned short*)out1)[(size_t)m * 4352 + (n - 4096)] = bv;
        }
      }
}

// ---------- causal depthwise conv (DCONV=4) + bias + silu ----------
__global__ __launch_bounds__(256) void k_conv(const unsigned short* __restrict__ xbc,
                                              const float* __restrict__ cw,
                                              const float* __restrict__ cb,
                                              unsigned short* __restrict__ xc){
  int idx = blockIdx.x * 256 + threadIdx.x;   // over 4096*544
  int tok = idx / 544;
  int ch0 = (idx - tok * 544) * 8;
  int l = tok & 2047;
  float acc[8];
  #pragma unroll
  for (int e = 0; e < 8; e++) acc[e] = cb[ch0 + e];
  #pragma unroll
  for (int d = 0; d < 4; d++){
    int ll = l - 3 + d;
    if (ll < 0) continue;
    bf16x8 v = *(const bf16x8*)(xbc + (size_t)(tok - 3 + d) * 4352 + ch0);
    #pragma unroll
    for (int e = 0; e < 8; e++)
      acc[e] += bf2f((unsigned short)v[e]) * cw[(ch0 + e) * 4 + d];
  }
  bf16x8 ov;
  #pragma unroll
  for (int e = 0; e < 8; e++){
    float a = acc[e];
    float s = a / (1.f + expf(-a));
    ov[e] = (short)f2bf(s);
  }
  *(bf16x8*)(xc + (size_t)tok * 4352 + ch0) = ov;
}

// inclusive prefix sum of 256 floats in LDS
__device__ __forceinline__ void cumsum256(float* s, int t){
  for (int off = 1; off < 256; off <<= 1){
    float v = (t >= off) ? s[t - off] : 0.f;
    __syncthreads();
    s[t] += v;
    __syncthreads();
  }
}

// ---------- per-(b,c,h) chunk states: states[p][n] = sum_j w[j] B[j][n] x[j][p] ----------
__global__ __launch_bounds__(256) void k_states(const unsigned short* __restrict__ xc,
                                                const float* __restrict__ dtw,
                                                const float* __restrict__ A_log,
                                                float* __restrict__ states,
                                                float* __restrict__ cdec){
  __shared__ unsigned short sBT[128][136];   // B^T: [n][j_local]
  __shared__ unsigned short swxT[64][136];   // (w*x)^T: [p][j_local]
  __shared__ float sdA[256];
  __shared__ float sdt[256];
  int t = threadIdx.x, w = t >> 6, l = t & 63;
  int h = blockIdx.x & 63, c = (blockIdx.x >> 6) & 7, b = blockIdx.x >> 9;
  int tok0 = b * 2048 + c * 256;

  float dtv = dtw[(size_t)(tok0 + t) * 64 + h];
  float Ah = -expf(A_log[h]);
  sdA[t] = dtv * Ah;
  sdt[t] = dtv;
  __syncthreads();
  cumsum256(sdA, t);
  float dA_end = sdA[255];
  if (t == 0) cdec[blockIdx.x] = expf(dA_end);

  f32x4 acc[4][2];
  #pragma unroll
  for (int i = 0; i < 4; i++){ acc[i][0] = (f32x4){0,0,0,0}; acc[i][1] = (f32x4){0,0,0,0}; }

  for (int jh = 0; jh < 2; jh++){
    #pragma unroll
    for (int q = 0; q < 8; q++){
      int id = t + q * 256;          // 2048 chunks of 8
      int jl = id >> 4, g = id & 15;
      int j = jh * 128 + jl;
      bf16x8 v = *(const bf16x8*)(xc + (size_t)(tok0 + j) * 4352 + 4096 + g * 8);
      #pragma unroll
      for (int e = 0; e < 8; e++) sBT[g * 8 + e][jl] = (unsigned short)v[e];
    }
    #pragma unroll
    for (int q = 0; q < 4; q++){
      int id = t + q * 256;          // 1024 chunks of 8
      int jl = id >> 3, g = id & 7;
      int j = jh * 128 + jl;
      float wj = expf(dA_end - sdA[j]) * sdt[j];
      bf16x8 v = *(const bf16x8*)(xc + (size_t)(tok0 + j) * 4352 + h * 64 + g * 8);
      #pragma unroll
      for (int e = 0; e < 8; e++) swxT[g * 8 + e][jl] = f2bf(bf2f((unsigned short)v[e]) * wj);
    }
    __syncthreads();
    #pragma unroll
    for (int ks = 0; ks < 4; ks++){
      int kk = ks * 32 + ((l >> 4) << 3);
      bf16x8 afr[4], bfr[2];
      #pragma unroll
      for (int pt = 0; pt < 4; pt++) afr[pt] = *(const bf16x8*)&swxT[pt * 16 + (l & 15)][kk];
      #pragma unroll
      for (int nt = 0; nt < 2; nt++) bfr[nt] = *(const bf16x8*)&sBT[(w * 2 + nt) * 16 + (l & 15)][kk];
      #pragma unroll
      for (int pt = 0; pt < 4; pt++)
        #pragma unroll
        for (int nt = 0; nt < 2; nt++)
          acc[pt][nt] = MFMA(afr[pt], bfr[nt], acc[pt][nt]);
    }
    __syncthreads();
  }
  float* sp = states + (size_t)blockIdx.x * 8192;
  #pragma unroll
  for (int pt = 0; pt < 4; pt++)
    #pragma unroll
    for (int nt = 0; nt < 2; nt++)
      #pragma unroll
      for (int r = 0; r < 4; r++){
        int p = pt * 16 + ((l >> 4) << 2) + r;
        int n = (w * 2 + nt) * 16 + (l & 15);
        sp[p * 128 + n] = acc[pt][nt][r];
      }
}

// ---------- sequential scan over 8 chunks per (b,h) ----------
__global__ __launch_bounds__(256) void k_scan(const float* __restrict__ states,
                                              const float* __restrict__ cdec,
                                              unsigned short* __restrict__ hprev){
  int b = blockIdx.x >> 6, h = blockIdx.x & 63;
  int t = threadIdx.x;
  float carry[32];
  #pragma unroll
  for (int i = 0; i < 32; i++) carry[i] = 0.f;
  for (int c = 0; c < 8; c++){
    int bch = (b * 8 + c) * 64 + h;
    size_t base = (size_t)bch * 8192;
    float d = cdec[bch];
    #pragma unroll
    for (int i = 0; i < 32; i++){
      int e = t + i * 256;
      hprev[base + e] = f2bf(carry[i]);
      carry[i] = carry[i] * d + states[base + e];
    }
  }
}

// ---------- per-(b,c,h): y = (scores@x) + (C*expf)@h_prev^T + Dp*x ----------
__global__ __launch_bounds__(256) void k_y(const unsigned short* __restrict__ xc,
                                           const float* __restrict__ dtw,
                                           const float* __restrict__ A_log,
                                           const unsigned short* __restrict__ hprev,
                                           const float* __restrict__ Dp,
                                           unsigned short* __restrict__ y){
  __shared__ unsigned short sxT[64][264];     // x^T: [p][j]
  __shared__ unsigned short sS[4][64][40];    // per-wave scores tile (64 i x 32 j)
  __shared__ float sdA[256];
  __shared__ float sdt[256];
  int t = threadIdx.x, w = t >> 6, l = t & 63;
  int h = blockIdx.x & 63, c = (blockIdx.x >> 6) & 7, b = blockIdx.x >> 9;
  int tok0 = b * 2048 + c * 256;
  int ib = w * 64;

  float dtv = dtw[(size_t)(tok0 + t) * 64 + h];
  float Ah = -expf(A_log[h]);
  sdA[t] = dtv * Ah;
  sdt[t] = dtv;
  __syncthreads();
  cumsum256(sdA, t);

  #pragma unroll
  for (int q = 0; q < 8; q++){
    int id = t + q * 256;
    int j = id >> 3, g = id & 7;
    bf16x8 v = *(const bf16x8*)(xc + (size_t)(tok0 + j) * 4352 + h * 64 + g * 8);
    #pragma unroll
    for (int e = 0; e < 8; e++) sxT[g * 8 + e][j] = (unsigned short)v[e];
  }
  __syncthreads();

  bf16x8 cfr[4][4];
  #pragma unroll
  for (int it = 0; it < 4; it++)
    #pragma unroll
    for (int kn = 0; kn < 4; kn++){
      int i = ib + it * 16 + (l & 15);
      int n = kn * 32 + ((l >> 4) << 3);
      cfr[it][kn] = *(const bf16x8*)(xc + (size_t)(tok0 + i) * 4352 + 4224 + n);
    }

  f32x4 acc[4][4];
  #pragma unroll
  for (int i = 0; i < 4; i++)
    #pragma unroll
    for (int j = 0; j < 4; j++) acc[i][j] = (f32x4){0,0,0,0};

  for (int jt = 0; jt < 8; jt++){
    f32x4 cb[4][2];
    #pragma unroll
    for (int i = 0; i < 4; i++){ cb[i][0] = (f32x4){0,0,0,0}; cb[i][1] = (f32x4){0,0,0,0}; }
    #pragma unroll
    for (int kn = 0; kn < 4; kn++){
      bf16x8 bfr[2];
      #pragma unroll
      for (int js = 0; js < 2; js++){
        int j = jt * 32 + js * 16 + (l & 15);
        int n = kn * 32 + ((l >> 4) << 3);
        bfr[js] = *(const bf16x8*)(xc + (size_t)(tok0 + j) * 4352 + 4096 + n);
      }
      #pragma unroll
      for (int it = 0; it < 4; it++)
        #pragma unroll
        for (int js = 0; js < 2; js++)
          cb[it][js] = MFMA(cfr[it][kn], bfr[js], cb[it][js]);
    }
    #pragma unroll
    for (int it = 0; it < 4; it++)
      #pragma unroll
      for (int js = 0; js < 2; js++)
        #pragma unroll
        for (int r = 0; r < 4; r++){
          int il = it * 16 + ((l >> 4) << 2) + r;
          int i = ib + il;
          int j = jt * 32 + js * 16 + (l & 15);
          float v = (i >= j) ? cb[it][js][r] * expf(sdA[i] - sdA[j]) * sdt[j] : 0.f;
          sS[w][il][js * 16 + (l & 15)] = f2bf(v);
        }
    int kk = ((l >> 4) << 3);
    bf16x8 sfr[4], xfr[4];
    #pragma unroll
    for (int it = 0; it < 4; it++) sfr[it] = *(const bf16x8*)&sS[w][it * 16 + (l & 15)][kk];
    #pragma unroll
    for (int pt = 0; pt < 4; pt++) xfr[pt] = *(const bf16x8*)&sxT[pt * 16 + (l & 15)][jt * 32 + kk];
    #pragma unroll
    for (int it = 0; it < 4; it++)
      #pragma unroll
      for (int pt = 0; pt < 4; pt++)
        acc[it][pt] = MFMA(sfr[it], xfr[pt], acc[it][pt]);
  }

  const unsigned short* hp = hprev + (size_t)blockIdx.x * 8192;
  float esc[4];
  #pragma unroll
  for (int it = 0; it < 4; it++) esc[it] = expf(sdA[ib + it * 16 + (l & 15)]);
  #pragma unroll
  for (int kn = 0; kn < 4; kn++){
    bf16x8 hfr[4];
    #pragma unroll
    for (int pt = 0; pt < 4; pt++){
      int p = pt * 16 + (l & 15);
      int n = kn * 32 + ((l >> 4) << 3);
      hfr[pt] = *(const bf16x8*)(hp + p * 128 + n);
    }
    #pragma unroll
    for (int it = 0; it < 4; it++){
      bf16x8 afv;
      #pragma unroll
      for (int e = 0; e < 8; e++)
        afv[e] = (short)f2bf(bf2f((unsigned short)cfr[it][kn][e]) * esc[it]);
      #pragma unroll
      for (int pt = 0; pt < 4; pt++)
        acc[it][pt] = MFMA(afv, hfr[pt], acc[it][pt]);
    }
  }

  float dph = Dp[h];
  #pragma unroll
  for (int it = 0; it < 4; it++)
    #pragma unroll
    for (int pt = 0; pt < 4; pt++)
      #pragma unroll
      for (int r = 0; r < 4; r++){
        int i = ib + it * 16 + ((l >> 4) << 2) + r;
        int p = pt * 16 + (l & 15);
        float xv = bf2f(sxT[p][i]);
        float v = acc[it][pt][r] + dph * xv;
        y[(size_t)(tok0 + i) * 4096 + h * 64 + p] = f2bf(v);
      }
}

// ---------- gate with silu(z), RMS-norm, * norm_w -> bf16 ----------
__global__ __launch_bounds__(256) void k_norm(const unsigned short* __restrict__ y,
                                              const unsigned short* __restrict__ zbuf,
                                              const float* __restrict__ norm_w,
                                              unsigned short* __restrict__ yn){
  int tok = blockIdx.x, t = threadIdx.x, w = t >> 6, l = t & 63;
  float vals[16];
  float ss = 0.f;
  #pragma unroll
  for (int q = 0; q < 2; q++){
    int col = q * 2048 + t * 8;
    bf16x8 yv = *(const bf16x8*)(y    + (size_t)tok * 4096 + col);
    bf16x8 zv = *(const bf16x8*)(zbuf + (size_t)tok * 4096 + col);
    #pragma unroll
    for (int e = 0; e < 8; e++){
      float yy = bf2f((unsigned short)yv[e]);
      float zz = bf2f((unsigned short)zv[e]);
      float g = yy * (zz / (1.f + expf(-zz)));
      vals[q * 8 + e] = g;
      ss += g * g;
    }
  }
  #pragma unroll
  for (int off = 32; off >= 1; off >>= 1) ss += __shfl_xor(ss, off, 64);
  __shared__ float red[4];
  if (l == 0) red[w] = ss;
  __syncthreads();
  float total = red[0] + red[1] + red[2] + red[3];
  float scale = rsqrtf(total * (1.f / 4096.f) + 1e-5f);
  #pragma unroll
  for (int q = 0; q < 2; q++){
    int col = q * 2048 + t * 8;
    bf16x8 ov;
    #pragma unroll
    for (int e = 0; e < 8; e++) ov[e] = (short)f2bf(vals[q * 8 + e] * scale * norm_w[col + e]);
    *(bf16x8*)(yn + (size_t)tok * 4096 + col) = ov;
  }
}

extern "C" void kernel_launch(void* const* d_in, const int* in_sizes, int n_in,
                              void* d_out, int out_size, void* d_ws, size_t ws_size,
                              hipStream_t stream) {
  const float* u       = (const float*)d_in[0];
  const float* W_in    = (const float*)d_in[1];
  const float* conv_w  = (const float*)d_in[2];
  const float* conv_b  = (const float*)d_in[3];
  const float* dt_bias = (const float*)d_in[4];
  const float* A_log   = (const float*)d_in[5];
  const float* Dp      = (const float*)d_in[6];
  const float* norm_w  = (const float*)d_in[7];
  const float* W_out   = (const float*)d_in[8];

  char* ws = (char*)d_ws;
  size_t off = 0;
  auto nxt = [&](size_t bytes) -> char* {
    char* r = ws + off;
    off += (bytes + 255) & ~(size_t)255;
    return r;
  };
  // R_Z: z (bf16) lives until k_norm; then reused for wout_bf
  char* RZ = nxt(4096ull * 4096 * 2);
  // R_X: xbc -> states(f32) -> ybuf
  char* RX = nxt(4096ull * 4352 * 2);
  // R_C: win_bf -> xc -> ynbuf
  char* RC = nxt(8512ull * 2048 * 2);     // 34.9MB (>= 4096*4352*2 = 35.7MB? no)
  // NOTE: RC must hold max(win_bf 34.9MB, xc 35.7MB) -> size by xc
  // (nxt above already advanced; fix by sizing to the max explicitly)
  // R_H: u_bf (16.8MB) -> hprev (16.8MB)
  char* RH = nxt(1024ull * 8192 * 2);
  float* dtw  = (float*)nxt(4096ull * 64 * 4);
  float* cdec = (float*)nxt(1024ull * 4);
  size_t need = off + (4096ull * 4352 * 2 - 8512ull * 2048 * 2) + 256; // slack for RC max-sizing
  (void)in_sizes; (void)n_in; (void)out_size;
  // Re-lay with correct RC size (deterministic, simple):
  off = 0;
  RZ = nxt(4096ull * 4096 * 2);
  RX = nxt(4096ull * 4352 * 2);
  RC = nxt(4096ull * 4352 * 2);           // 35.7MB >= win_bf 34.9MB and xc
  RH = nxt(1024ull * 8192 * 2);
  dtw  = (float*)nxt(4096ull * 64 * 4);
  cdec = (float*)nxt(1024ull * 4);
  need = off;
  if (ws_size < need) return;

  unsigned short* zbuf    = (unsigned short*)RZ;
  unsigned short* wout_bf = (unsigned short*)RZ;   // after k_norm
  unsigned short* xbc     = (unsigned short*)RX;
  float*          states  = (float*)RX;
  unsigned short* ybuf    = (unsigned short*)RX;
  unsigned short* win_bf  = (unsigned short*)RC;
  unsigned short* xc      = (unsigned short*)RC;
  unsigned short* ynbuf   = (unsigned short*)RC;
  unsigned short* u_bf    = (unsigned short*)RH;
  unsigned short* hprev   = (unsigned short*)RH;

  // pre-cast operands to bf16 (into dead windows)
  k_f2bf<<<8192,  256, 0, stream>>>(u,    u_bf,   4096 * 2048);
  k_f2bf<<<17024, 256, 0, stream>>>(W_in, win_bf, 8512 * 2048);
  k_dt<<<1024, 256, 0, stream>>>(u, W_in, dt_bias, dtw);
  // in-proj GEMM: M=4096, N=8448, K=2048; grid 66x32 (div by 8)
  k_gemm_bf<1><<<dim3(66, 32), 256, 0, stream>>>(u_bf, win_bf, zbuf, xbc, 4096, 8448, 2048);
  k_conv<<<8704, 256, 0, stream>>>(xbc, conv_w, conv_b, xc);
  k_states<<<1024, 256, 0, stream>>>(xc, dtw, A_log, states, cdec);
  k_scan<<<128, 256, 0, stream>>>(states, cdec, hprev);
  k_y<<<1024, 256, 0, stream>>>(xc, dtw, A_log, hprev, Dp, ybuf);
  k_norm<<<4096, 256, 0, stream>>>(ybuf, zbuf, norm_w, ynbuf);
  // out-proj: cast W_out into RZ (z dead), then GEMM M=4096,N=2048,K=4096; grid 16x32
  k_f2bf<<<8192, 256, 0, stream>>>(W_out, wout_bf, 2048 * 4096);
  k_gemm_bf<0><<<dim3(16, 32), 256, 0, stream>>>(ynbuf, wout_bf, d_out, nullptr, 4096, 2048, 4096);
}

// Round 5
// 711.100 us; speedup vs baseline: 1.2530x; 1.0436x over previous
//
#include <hip/hip_runtime.h>
#include <hip/hip_bf16.h>

// ---------------- Mamba2 block (B=2, L=2048, D_MODEL=2048, D_INNER=4096,
// NH=64, HP=64, DS=128, G=1, DCONV=4, CHUNK=256) ----------------
// Round 4: gemm1 -> 256x256/BK=64 2-phase-prefetch (8 waves, 128KB LDS dbuf,
// global_load_lds staging, 1 barrier per K-tile). k_scan 128->512 blocks.

typedef __attribute__((ext_vector_type(8))) short bf16x8;
typedef __attribute__((ext_vector_type(4))) float f32x4;
typedef __attribute__((ext_vector_type(4))) float float4v;

#define MFMA(a,b,c) __builtin_amdgcn_mfma_f32_16x16x32_bf16((a),(b),(c),0,0,0)

#define GLOAD_LDS16(gp, lp) \
  __builtin_amdgcn_global_load_lds((const __attribute__((address_space(1))) void*)(gp), \
                                   (__attribute__((address_space(3))) void*)(lp), 16, 0, 0)

__device__ __forceinline__ float bf2f(unsigned short u){
  union { unsigned int i; float f; } v; v.i = ((unsigned int)u) << 16; return v.f;
}
__device__ __forceinline__ unsigned short f2bf(float f){
  union { float f; unsigned int i; } v; v.f = f;
  unsigned int x = v.i;
  return (unsigned short)((x + 0x7fffu + ((x >> 16) & 1u)) >> 16);
}

// ---------- f32 -> bf16 (vectorized cast) ----------
__global__ __launch_bounds__(256) void k_f2bf(const float* __restrict__ in,
                                              unsigned short* __restrict__ out, int n){
  int i = (blockIdx.x * 256 + threadIdx.x) * 4;
  if (i >= n) return;
  float4v v = *(const float4v*)(in + i);
  union { unsigned short u[4]; unsigned long long ll; } o;
  o.u[0] = f2bf(v.x); o.u[1] = f2bf(v.y); o.u[2] = f2bf(v.z); o.u[3] = f2bf(v.w);
  *(unsigned long long*)(out + i) = o.ll;
}

// ---------- dt = softplus(u @ Wdt^T + dt_bias), f32 ----------
__global__ __launch_bounds__(256) void k_dt(const float* __restrict__ u,
                                            const float* __restrict__ Win,
                                            const float* __restrict__ dt_bias,
                                            float* __restrict__ dt_out){
  __shared__ float su[4][2048];
  int t = threadIdx.x, w = t >> 6, l = t & 63;
  int m0 = blockIdx.x * 4;
  #pragma unroll
  for (int q = 0; q < 8; q++){
    int id = t + q * 256;
    int r = id >> 9, c4 = id & 511;
    ((float4v*)su[r])[c4] = ((const float4v*)(u + (size_t)(m0 + r) * 2048))[c4];
  }
  __syncthreads();
  int m = m0 + w;
  for (int h = 0; h < 64; h++){
    const float* wr = Win + (size_t)(8448 + h) * 2048;
    float acc = 0.f;
    #pragma unroll
    for (int i = 0; i < 8; i++){
      int k4 = l + i * 64;
      float4v a = ((const float4v*)su[w])[k4];
      float4v b = ((const float4v*)wr)[k4];
      acc += a.x * b.x + a.y * b.y + a.z * b.z + a.w * b.w;
    }
    #pragma unroll
    for (int off = 32; off >= 1; off >>= 1) acc += __shfl_xor(acc, off, 64);
    if (l == 0){
      float x = acc + dt_bias[h];
      dt_out[(size_t)m * 64 + h] = (x > 20.f) ? x : log1pf(expf(x));
    }
  }
}

// ---------- gemm1: 256x256 tile, BK=64, 2-phase prefetch, split bf16 store ----------
// C[m][n] = sum_k A[m][k]*B[n][k]; M=4096, N=8448, K=2048. Grid (33,16), 512 thr.
__global__ __launch_bounds__(512, 2) void k_gemm256(const unsigned short* __restrict__ A,
                                                    const unsigned short* __restrict__ B,
                                                    unsigned short* __restrict__ zbuf,
                                                    unsigned short* __restrict__ xbc,
                                                    int K){
  __shared__ unsigned short lds[65536];   // 128KB: [buf][A 16384 | B 16384]
  int t = threadIdx.x, wid = t >> 6, l = t & 63;
  int wr = wid >> 2, wc = wid & 3;        // wave grid 2(M) x 4(N)
  // bijective XCD swizzle over 528 blocks
  int nbx = gridDim.x;
  int bid = blockIdx.y * nbx + blockIdx.x;
  int cpx = (nbx * gridDim.y) >> 3;
  int sbid = (bid & 7) * cpx + (bid >> 3);
  int bx = sbid % nbx, by = sbid / nbx;
  int mbase = by * 256, nbase = bx * 256;

  const unsigned short* Ab = A + (size_t)mbase * K;
  const unsigned short* Bb = B + (size_t)nbase * K;

  f32x4 acc[8][4];
  #pragma unroll
  for (int i = 0; i < 8; i++)
    #pragma unroll
    for (int j = 0; j < 4; j++) acc[i][j] = (f32x4){0.f,0.f,0.f,0.f};

  // stage one K-tile (256x64 of A and B) into buffer c
  auto STAGE = [&](int c, int kb){
    unsigned short* la = &lds[c * 32768];
    unsigned short* lb = la + 16384;
    #pragma unroll
    for (int q = 0; q < 4; q++){
      int ch = t + q * 512;                 // 2048 chunks of 16B per matrix
      int r = ch >> 3, cb = (ch & 7) * 8;
      GLOAD_LDS16(Ab + (size_t)r * K + kb + cb, la + ch * 8);
      GLOAD_LDS16(Bb + (size_t)r * K + kb + cb, lb + ch * 8);
    }
  };
  auto COMPUTE = [&](int c){
    const unsigned short* la = &lds[c * 32768];
    const unsigned short* lb = la + 16384;
    #pragma unroll
    for (int ks = 0; ks < 64; ks += 32){
      int kk = ks + ((l >> 4) << 3);
      bf16x8 af[8], bfv[4];
      #pragma unroll
      for (int i = 0; i < 8; i++)
        af[i] = *(const bf16x8*)&la[(wr * 128 + i * 16 + (l & 15)) * 64 + kk];
      #pragma unroll
      for (int j = 0; j < 4; j++)
        bfv[j] = *(const bf16x8*)&lb[(wc * 64 + j * 16 + (l & 15)) * 64 + kk];
      #pragma unroll
      for (int i = 0; i < 8; i++)
        #pragma unroll
        for (int j = 0; j < 4; j++)
          acc[i][j] = MFMA(af[i], bfv[j], acc[i][j]);
    }
  };

  int cur = 0;
  STAGE(0, 0);
  __syncthreads();                          // vmcnt0+lgkm0+barrier
  for (int kb = 64; kb < K; kb += 64){
    STAGE(cur ^ 1, kb);                     // issue next tile first
    COMPUTE(cur);                           // then compute current
    __syncthreads();                        // drains the (long-in-flight) stage
    cur ^= 1;
  }
  COMPUTE(cur);

  #pragma unroll
  for (int i = 0; i < 8; i++)
    #pragma unroll
    for (int j = 0; j < 4; j++)
      #pragma unroll
      for (int r = 0; r < 4; r++){
        int m = mbase + wr * 128 + i * 16 + ((l >> 4) << 2) + r;
        int n = nbase + wc * 64 + j * 16 + (l & 15);
        unsigned short v = f2bf(acc[i][j][r]);
        if (n < 4096) zbuf[(size_t)m * 4096 + n] = v;
        else          xbc[(size_t)m * 4352 + (n - 4096)] = v;
      }
}

// ---------- gemm2 (128x128 m97-structure): out = yn @ W_out^T, f32 out ----------
__global__ __launch_bounds__(256) void k_gemm128(const unsigned short* __restrict__ A,
                                                 const unsigned short* __restrict__ B,
                                                 float* __restrict__ C,
                                                 int N, int K){
  __shared__ unsigned short sA[128 * 64];
  __shared__ unsigned short sB[128 * 64];
  int t = threadIdx.x, w = t >> 6, l = t & 63;
  int nbx = gridDim.x;
  int bid = blockIdx.y * nbx + blockIdx.x;
  int cpx = (nbx * gridDim.y) >> 3;
  int sbid = (bid & 7) * cpx + (bid >> 3);
  int bx = sbid % nbx, by = sbid / nbx;
  int mbase = by * 128, nbase = bx * 128;
  int wr = (w >> 1) * 64, wc = (w & 1) * 64;

  f32x4 acc[4][4];
  #pragma unroll
  for (int i = 0; i < 4; i++)
    #pragma unroll
    for (int j = 0; j < 4; j++) acc[i][j] = (f32x4){0.f,0.f,0.f,0.f};

  const unsigned short* Ab = A + (size_t)mbase * K;
  const unsigned short* Bb = B + (size_t)nbase * K;
  int r0 = t >> 3, g0 = (t & 7) * 8;
  for (int kb = 0; kb < K; kb += 64){
    #pragma unroll
    for (int q = 0; q < 4; q++){
      int c = t + q * 256;
      int r = r0 + q * 32;
      GLOAD_LDS16(Ab + (size_t)r * K + kb + g0, &sA[c * 8]);
      GLOAD_LDS16(Bb + (size_t)r * K + kb + g0, &sB[c * 8]);
    }
    __syncthreads();
    #pragma unroll
    for (int ks = 0; ks < 64; ks += 32){
      int kk = ks + ((l >> 4) << 3);
      bf16x8 af[4], bfv[4];
      #pragma unroll
      for (int it = 0; it < 4; it++) af[it]  = *(const bf16x8*)&sA[(wr + it * 16 + (l & 15)) * 64 + kk];
      #pragma unroll
      for (int nt = 0; nt < 4; nt++) bfv[nt] = *(const bf16x8*)&sB[(wc + nt * 16 + (l & 15)) * 64 + kk];
      #pragma unroll
      for (int it = 0; it < 4; it++)
        #pragma unroll
        for (int nt = 0; nt < 4; nt++)
          acc[it][nt] = MFMA(af[it], bfv[nt], acc[it][nt]);
    }
    __syncthreads();
  }
  #pragma unroll
  for (int it = 0; it < 4; it++)
    #pragma unroll
    for (int nt = 0; nt < 4; nt++)
      #pragma unroll
      for (int r = 0; r < 4; r++){
        int m = mbase + wr + it * 16 + ((l >> 4) << 2) + r;
        int n = nbase + wc + nt * 16 + (l & 15);
        C[(size_t)m * N + n] = acc[it][nt][r];
      }
}

// ---------- causal depthwise conv (DCONV=4) + bias + silu ----------
__global__ __launch_bounds__(256) void k_conv(const unsigned short* __restrict__ xbc,
                                              const float* __restrict__ cw,
                                              const float* __restrict__ cb,
                                              unsigned short* __restrict__ xc){
  int idx = blockIdx.x * 256 + threadIdx.x;   // over 4096*544
  int tok = idx / 544;
  int ch0 = (idx - tok * 544) * 8;
  int l = tok & 2047;
  float acc[8];
  #pragma unroll
  for (int e = 0; e < 8; e++) acc[e] = cb[ch0 + e];
  #pragma unroll
  for (int d = 0; d < 4; d++){
    int ll = l - 3 + d;
    if (ll < 0) continue;
    bf16x8 v = *(const bf16x8*)(xbc + (size_t)(tok - 3 + d) * 4352 + ch0);
    #pragma unroll
    for (int e = 0; e < 8; e++)
      acc[e] += bf2f((unsigned short)v[e]) * cw[(ch0 + e) * 4 + d];
  }
  bf16x8 ov;
  #pragma unroll
  for (int e = 0; e < 8; e++){
    float a = acc[e];
    float s = a / (1.f + expf(-a));
    ov[e] = (short)f2bf(s);
  }
  *(bf16x8*)(xc + (size_t)tok * 4352 + ch0) = ov;
}

// inclusive prefix sum of 256 floats in LDS
__device__ __forceinline__ void cumsum256(float* s, int t){
  for (int off = 1; off < 256; off <<= 1){
    float v = (t >= off) ? s[t - off] : 0.f;
    __syncthreads();
    s[t] += v;
    __syncthreads();
  }
}

// ---------- per-(b,c,h) chunk states: states[p][n] = sum_j w[j] B[j][n] x[j][p] ----------
__global__ __launch_bounds__(256) void k_states(const unsigned short* __restrict__ xc,
                                                const float* __restrict__ dtw,
                                                const float* __restrict__ A_log,
                                                float* __restrict__ states,
                                                float* __restrict__ cdec){
  __shared__ unsigned short sBT[128][136];
  __shared__ unsigned short swxT[64][136];
  __shared__ float sdA[256];
  __shared__ float sdt[256];
  int t = threadIdx.x, w = t >> 6, l = t & 63;
  int h = blockIdx.x & 63, c = (blockIdx.x >> 6) & 7, b = blockIdx.x >> 9;
  int tok0 = b * 2048 + c * 256;

  float dtv = dtw[(size_t)(tok0 + t) * 64 + h];
  float Ah = -expf(A_log[h]);
  sdA[t] = dtv * Ah;
  sdt[t] = dtv;
  __syncthreads();
  cumsum256(sdA, t);
  float dA_end = sdA[255];
  if (t == 0) cdec[blockIdx.x] = expf(dA_end);

  f32x4 acc[4][2];
  #pragma unroll
  for (int i = 0; i < 4; i++){ acc[i][0] = (f32x4){0,0,0,0}; acc[i][1] = (f32x4){0,0,0,0}; }

  for (int jh = 0; jh < 2; jh++){
    #pragma unroll
    for (int q = 0; q < 8; q++){
      int id = t + q * 256;
      int jl = id >> 4, g = id & 15;
      int j = jh * 128 + jl;
      bf16x8 v = *(const bf16x8*)(xc + (size_t)(tok0 + j) * 4352 + 4096 + g * 8);
      #pragma unroll
      for (int e = 0; e < 8; e++) sBT[g * 8 + e][jl] = (unsigned short)v[e];
    }
    #pragma unroll
    for (int q = 0; q < 4; q++){
      int id = t + q * 256;
      int jl = id >> 3, g = id & 7;
      int j = jh * 128 + jl;
      float wj = expf(dA_end - sdA[j]) * sdt[j];
      bf16x8 v = *(const bf16x8*)(xc + (size_t)(tok0 + j) * 4352 + h * 64 + g * 8);
      #pragma unroll
      for (int e = 0; e < 8; e++) swxT[g * 8 + e][jl] = f2bf(bf2f((unsigned short)v[e]) * wj);
    }
    __syncthreads();
    #pragma unroll
    for (int ks = 0; ks < 4; ks++){
      int kk = ks * 32 + ((l >> 4) << 3);
      bf16x8 afr[4], bfr[2];
      #pragma unroll
      for (int pt = 0; pt < 4; pt++) afr[pt] = *(const bf16x8*)&swxT[pt * 16 + (l & 15)][kk];
      #pragma unroll
      for (int nt = 0; nt < 2; nt++) bfr[nt] = *(const bf16x8*)&sBT[(w * 2 + nt) * 16 + (l & 15)][kk];
      #pragma unroll
      for (int pt = 0; pt < 4; pt++)
        #pragma unroll
        for (int nt = 0; nt < 2; nt++)
          acc[pt][nt] = MFMA(afr[pt], bfr[nt], acc[pt][nt]);
    }
    __syncthreads();
  }
  float* sp = states + (size_t)blockIdx.x * 8192;
  #pragma unroll
  for (int pt = 0; pt < 4; pt++)
    #pragma unroll
    for (int nt = 0; nt < 2; nt++)
      #pragma unroll
      for (int r = 0; r < 4; r++){
        int p = pt * 16 + ((l >> 4) << 2) + r;
        int n = (w * 2 + nt) * 16 + (l & 15);
        sp[p * 128 + n] = acc[pt][nt][r];
      }
}

// ---------- sequential scan over 8 chunks per (b,h,quarter): 512 blocks ----------
__global__ __launch_bounds__(256) void k_scan(const float* __restrict__ states,
                                              const float* __restrict__ cdec,
                                              unsigned short* __restrict__ hprev){
  int q = blockIdx.x & 3, bh = blockIdx.x >> 2;
  int b = bh >> 6, h = bh & 63;
  int t = threadIdx.x;
  float carry[8];
  #pragma unroll
  for (int i = 0; i < 8; i++) carry[i] = 0.f;
  for (int c = 0; c < 8; c++){
    int bch = (b * 8 + c) * 64 + h;
    size_t base = (size_t)bch * 8192 + q * 2048;
    float d = cdec[bch];
    #pragma unroll
    for (int i = 0; i < 8; i++){
      int e = t + i * 256;
      hprev[base + e] = f2bf(carry[i]);
      carry[i] = carry[i] * d + states[base + e];
    }
  }
}

// ---------- per-(b,c,h): y = (scores@x) + (C*expf)@h_prev^T + Dp*x ----------
__global__ __launch_bounds__(256) void k_y(const unsigned short* __restrict__ xc,
                                           const float* __restrict__ dtw,
                                           const float* __restrict__ A_log,
                                           const unsigned short* __restrict__ hprev,
                                           const float* __restrict__ Dp,
                                           unsigned short* __restrict__ y){
  __shared__ unsigned short sxT[64][264];
  __shared__ unsigned short sS[4][64][40];
  __shared__ float sdA[256];
  __shared__ float sdt[256];
  int t = threadIdx.x, w = t >> 6, l = t & 63;
  int h = blockIdx.x & 63, c = (blockIdx.x >> 6) & 7, b = blockIdx.x >> 9;
  int tok0 = b * 2048 + c * 256;
  int ib = w * 64;

  float dtv = dtw[(size_t)(tok0 + t) * 64 + h];
  float Ah = -expf(A_log[h]);
  sdA[t] = dtv * Ah;
  sdt[t] = dtv;
  __syncthreads();
  cumsum256(sdA, t);

  #pragma unroll
  for (int q = 0; q < 8; q++){
    int id = t + q * 256;
    int j = id >> 3, g = id & 7;
    bf16x8 v = *(const bf16x8*)(xc + (size_t)(tok0 + j) * 4352 + h * 64 + g * 8);
    #pragma unroll
    for (int e = 0; e < 8; e++) sxT[g * 8 + e][j] = (unsigned short)v[e];
  }
  __syncthreads();

  bf16x8 cfr[4][4];
  #pragma unroll
  for (int it = 0; it < 4; it++)
    #pragma unroll
    for (int kn = 0; kn < 4; kn++){
      int i = ib + it * 16 + (l & 15);
      int n = kn * 32 + ((l >> 4) << 3);
      cfr[it][kn] = *(const bf16x8*)(xc + (size_t)(tok0 + i) * 4352 + 4224 + n);
    }

  f32x4 acc[4][4];
  #pragma unroll
  for (int i = 0; i < 4; i++)
    #pragma unroll
    for (int j = 0; j < 4; j++) acc[i][j] = (f32x4){0,0,0,0};

  for (int jt = 0; jt < 8; jt++){
    f32x4 cb[4][2];
    #pragma unroll
    for (int i = 0; i < 4; i++){ cb[i][0] = (f32x4){0,0,0,0}; cb[i][1] = (f32x4){0,0,0,0}; }
    #pragma unroll
    for (int kn = 0; kn < 4; kn++){
      bf16x8 bfr[2];
      #pragma unroll
      for (int js = 0; js < 2; js++){
        int j = jt * 32 + js * 16 + (l & 15);
        int n = kn * 32 + ((l >> 4) << 3);
        bfr[js] = *(const bf16x8*)(xc + (size_t)(tok0 + j) * 4352 + 4096 + n);
      }
      #pragma unroll
      for (int it = 0; it < 4; it++)
        #pragma unroll
        for (int js = 0; js < 2; js++)
          cb[it][js] = MFMA(cfr[it][kn], bfr[js], cb[it][js]);
    }
    #pragma unroll
    for (int it = 0; it < 4; it++)
      #pragma unroll
      for (int js = 0; js < 2; js++)
        #pragma unroll
        for (int r = 0; r < 4; r++){
          int il = it * 16 + ((l >> 4) << 2) + r;
          int i = ib + il;
          int j = jt * 32 + js * 16 + (l & 15);
          float v = (i >= j) ? cb[it][js][r] * expf(sdA[i] - sdA[j]) * sdt[j] : 0.f;
          sS[w][il][js * 16 + (l & 15)] = f2bf(v);
        }
    int kk = ((l >> 4) << 3);
    bf16x8 sfr[4], xfr[4];
    #pragma unroll
    for (int it = 0; it < 4; it++) sfr[it] = *(const bf16x8*)&sS[w][it * 16 + (l & 15)][kk];
    #pragma unroll
    for (int pt = 0; pt < 4; pt++) xfr[pt] = *(const bf16x8*)&sxT[pt * 16 + (l & 15)][jt * 32 + kk];
    #pragma unroll
    for (int it = 0; it < 4; it++)
      #pragma unroll
      for (int pt = 0; pt < 4; pt++)
        acc[it][pt] = MFMA(sfr[it], xfr[pt], acc[it][pt]);
  }

  const unsigned short* hp = hprev + (size_t)blockIdx.x * 8192;
  float esc[4];
  #pragma unroll
  for (int it = 0; it < 4; it++) esc[it] = expf(sdA[ib + it * 16 + (l & 15)]);
  #pragma unroll
  for (int kn = 0; kn < 4; kn++){
    bf16x8 hfr[4];
    #pragma unroll
    for (int pt = 0; pt < 4; pt++){
      int p = pt * 16 + (l & 15);
      int n = kn * 32 + ((l >> 4) << 3);
      hfr[pt] = *(const bf16x8*)(hp + p * 128 + n);
    }
    #pragma unroll
    for (int it = 0; it < 4; it++){
      bf16x8 afv;
      #pragma unroll
      for (int e = 0; e < 8; e++)
        afv[e] = (short)f2bf(bf2f((unsigned short)cfr[it][kn][e]) * esc[it]);
      #pragma unroll
      for (int pt = 0; pt < 4; pt++)
        acc[it][pt] = MFMA(afv, hfr[pt], acc[it][pt]);
    }
  }

  float dph = Dp[h];
  #pragma unroll
  for (int it = 0; it < 4; it++)
    #pragma unroll
    for (int pt = 0; pt < 4; pt++)
      #pragma unroll
      for (int r = 0; r < 4; r++){
        int i = ib + it * 16 + ((l >> 4) << 2) + r;
        int p = pt * 16 + (l & 15);
        float xv = bf2f(sxT[p][i]);
        float v = acc[it][pt][r] + dph * xv;
        y[(size_t)(tok0 + i) * 4096 + h * 64 + p] = f2bf(v);
      }
}

// ---------- gate with silu(z), RMS-norm, * norm_w -> bf16 ----------
__global__ __launch_bounds__(256) void k_norm(const unsigned short* __restrict__ y,
                                              const unsigned short* __restrict__ zbuf,
                                              const float* __restrict__ norm_w,
                                              unsigned short* __restrict__ yn){
  int tok = blockIdx.x, t = threadIdx.x, w = t >> 6, l = t & 63;
  float vals[16];
  float ss = 0.f;
  #pragma unroll
  for (int q = 0; q < 2; q++){
    int col = q * 2048 + t * 8;
    bf16x8 yv = *(const bf16x8*)(y    + (size_t)tok * 4096 + col);
    bf16x8 zv = *(const bf16x8*)(zbuf + (size_t)tok * 4096 + col);
    #pragma unroll
    for (int e = 0; e < 8; e++){
      float yy = bf2f((unsigned short)yv[e]);
      float zz = bf2f((unsigned short)zv[e]);
      float g = yy * (zz / (1.f + expf(-zz)));
      vals[q * 8 + e] = g;
      ss += g * g;
    }
  }
  #pragma unroll
  for (int off = 32; off >= 1; off >>= 1) ss += __shfl_xor(ss, off, 64);
  __shared__ float red[4];
  if (l == 0) red[w] = ss;
  __syncthreads();
  float total = red[0] + red[1] + red[2] + red[3];
  float scale = rsqrtf(total * (1.f / 4096.f) + 1e-5f);
  #pragma unroll
  for (int q = 0; q < 2; q++){
    int col = q * 2048 + t * 8;
    bf16x8 ov;
    #pragma unroll
    for (int e = 0; e < 8; e++) ov[e] = (short)f2bf(vals[q * 8 + e] * scale * norm_w[col + e]);
    *(bf16x8*)(yn + (size_t)tok * 4096 + col) = ov;
  }
}

extern "C" void kernel_launch(void* const* d_in, const int* in_sizes, int n_in,
                              void* d_out, int out_size, void* d_ws, size_t ws_size,
                              hipStream_t stream) {
  const float* u       = (const float*)d_in[0];
  const float* W_in    = (const float*)d_in[1];
  const float* conv_w  = (const float*)d_in[2];
  const float* conv_b  = (const float*)d_in[3];
  const float* dt_bias = (const float*)d_in[4];
  const float* A_log   = (const float*)d_in[5];
  const float* Dp      = (const float*)d_in[6];
  const float* norm_w  = (const float*)d_in[7];
  const float* W_out   = (const float*)d_in[8];

  char* ws = (char*)d_ws;
  size_t off = 0;
  auto nxt = [&](size_t bytes) -> char* {
    char* r = ws + off;
    off += (bytes + 255) & ~(size_t)255;
    return r;
  };
  char* RZ = nxt(4096ull * 4096 * 2);   // zbuf -> wout_bf
  char* RX = nxt(4096ull * 4352 * 2);   // xbc -> states(f32) -> ybuf
  char* RC = nxt(4096ull * 4352 * 2);   // win_bf -> xc -> ynbuf
  char* RH = nxt(1024ull * 8192 * 2);   // u_bf -> hprev
  float* dtw  = (float*)nxt(4096ull * 64 * 4);
  float* cdec = (float*)nxt(1024ull * 4);
  size_t need = off;
  (void)in_sizes; (void)n_in; (void)out_size;
  if (ws_size < need) return;

  unsigned short* zbuf    = (unsigned short*)RZ;
  unsigned short* wout_bf = (unsigned short*)RZ;   // after k_norm
  unsigned short* xbc     = (unsigned short*)RX;
  float*          states  = (float*)RX;
  unsigned short* ybuf    = (unsigned short*)RX;
  unsigned short* win_bf  = (unsigned short*)RC;
  unsigned short* xc      = (unsigned short*)RC;
  unsigned short* ynbuf   = (unsigned short*)RC;
  unsigned short* u_bf    = (unsigned short*)RH;
  unsigned short* hprev   = (unsigned short*)RH;

  k_f2bf<<<8192,  256, 0, stream>>>(u,    u_bf,   4096 * 2048);
  k_f2bf<<<17024, 256, 0, stream>>>(W_in, win_bf, 8512 * 2048);
  k_dt<<<1024, 256, 0, stream>>>(u, W_in, dt_bias, dtw);
  k_gemm256<<<dim3(33, 16), 512, 0, stream>>>(u_bf, win_bf, zbuf, xbc, 2048);
  k_conv<<<8704, 256, 0, stream>>>(xbc, conv_w, conv_b, xc);
  k_states<<<1024, 256, 0, stream>>>(xc, dtw, A_log, states, cdec);
  k_scan<<<512, 256, 0, stream>>>(states, cdec, hprev);
  k_y<<<1024, 256, 0, stream>>>(xc, dtw, A_log, hprev, Dp, ybuf);
  k_norm<<<4096, 256, 0, stream>>>(ybuf, zbuf, norm_w, ynbuf);
  k_f2bf<<<8192, 256, 0, stream>>>(W_out, wout_bf, 2048 * 4096);
  k_gemm128<<<dim3(16, 32), 256, 0, stream>>>(ynbuf, wout_bf, (float*)d_out, 2048, 4096);
}

// Round 6
// 634.466 us; speedup vs baseline: 1.4043x; 1.1208x over previous
//
#include <hip/hip_runtime.h>
#include <hip/hip_bf16.h>

// ---------------- Mamba2 block (B=2, L=2048, D_MODEL=2048, D_INNER=4096,
// NH=64, HP=64, DS=128, G=1, DCONV=4, CHUNK=256) ----------------
// Round 5: GEMMs -> counted-vmcnt double-buffer pipeline (raw s_barrier +
// vmcnt(N), never 0 in loop) + T2 st_16x32 swizzle (pre-swizzled global src,
// swizzled ds_read). dt via small MFMA GEMM instead of serial wave loop.

typedef __attribute__((ext_vector_type(8))) short bf16x8;
typedef __attribute__((ext_vector_type(4))) float f32x4;
typedef __attribute__((ext_vector_type(4))) float float4v;

#define MFMA(a,b,c) __builtin_amdgcn_mfma_f32_16x16x32_bf16((a),(b),(c),0,0,0)

#define GLOAD_LDS16(gp, lp) \
  __builtin_amdgcn_global_load_lds((const __attribute__((address_space(1))) void*)(gp), \
                                   (__attribute__((address_space(3))) void*)(lp), 16, 0, 0)

__device__ __forceinline__ float bf2f(unsigned short u){
  union { unsigned int i; float f; } v; v.i = ((unsigned int)u) << 16; return v.f;
}
__device__ __forceinline__ unsigned short f2bf(float f){
  union { float f; unsigned int i; } v; v.f = f;
  unsigned int x = v.i;
  return (unsigned short)((x + 0x7fffu + ((x >> 16) & 1u)) >> 16);
}

// ---------- f32 -> bf16 (vectorized cast) ----------
__global__ __launch_bounds__(256) void k_f2bf(const float* __restrict__ in,
                                              unsigned short* __restrict__ out, int n){
  int i = (blockIdx.x * 256 + threadIdx.x) * 4;
  if (i >= n) return;
  float4v v = *(const float4v*)(in + i);
  union { unsigned short u[4]; unsigned long long ll; } o;
  o.u[0] = f2bf(v.x); o.u[1] = f2bf(v.y); o.u[2] = f2bf(v.z); o.u[3] = f2bf(v.w);
  *(unsigned long long*)(out + i) = o.ll;
}

// ---------- counted-vmcnt GEMM: C[m][n] = sum_k A[m][k]*B[n][k] ----------
// BN=256 fixed, BK=64, 512 threads (8 waves, 2M x 4N).
// BM=256 (SPLIT=1: bf16 split store z/xbc) or BM=128 (SPLIT=0: f32 out).
// T2 st_16x32 swizzle: LDS linear dest, inverse-swizzled global src, swizzled read.
template<int BM, int SPLIT>
__global__ __launch_bounds__(512, 2) void k_gcnt(const unsigned short* __restrict__ A,
                                                 const unsigned short* __restrict__ B,
                                                 void* __restrict__ out0,
                                                 void* __restrict__ out1,
                                                 int N, int K){
  constexpr int MI = BM / 32;                 // A frags per wave (M dir)
  __shared__ unsigned short lds[2 * (BM + 256) * 64];
  int t = threadIdx.x, wid = t >> 6, l = t & 63;
  int wr = wid >> 2, wc = wid & 3;            // wave grid 2(M) x 4(N)
  // bijective XCD swizzle (grid product divisible by 8)
  int nbx = gridDim.x;
  int bid = blockIdx.y * nbx + blockIdx.x;
  int cpx = (nbx * gridDim.y) >> 3;
  int sbid = (bid & 7) * cpx + (bid >> 3);
  int bx = sbid % nbx, by = sbid / nbx;
  int mbase = by * BM, nbase = bx * 256;

  const unsigned short* Ab = A + (size_t)mbase * K;
  const unsigned short* Bb = B + (size_t)nbase * K;

  f32x4 acc[MI][4];
  #pragma unroll
  for (int i = 0; i < MI; i++)
    #pragma unroll
    for (int j = 0; j < 4; j++) acc[i][j] = (f32x4){0.f,0.f,0.f,0.f};

  // stage one K-tile into buffer c; LDS dest linear, global src inverse-swizzled
  auto STAGE = [&](int c, int kb){
    char* la = (char*)&lds[c * (BM + 256) * 64];
    char* lb = la + BM * 128;
    #pragma unroll
    for (int q = 0; q < BM / 64; q++){        // A: BM*8 chunks of 16B
      int o = (t + q * 512) * 16;
      int bs = o ^ ((((unsigned)o >> 9) & 1) << 5);
      int r = bs >> 7, cb = bs & 127;
      GLOAD_LDS16((const char*)Ab + (size_t)r * (K * 2) + (size_t)kb * 2 + cb, la + o);
    }
    #pragma unroll
    for (int q = 0; q < 4; q++){              // B: 2048 chunks of 16B
      int o = (t + q * 512) * 16;
      int bs = o ^ ((((unsigned)o >> 9) & 1) << 5);
      int r = bs >> 7, cb = bs & 127;
      GLOAD_LDS16((const char*)Bb + (size_t)r * (K * 2) + (size_t)kb * 2 + cb, lb + o);
    }
  };
  // swizzled fragment read: region-local row r, byte-col kbyte (16B aligned)
  auto LD8 = [&](const char* region, int r, int kbyte) -> bf16x8 {
    int addr = r * 128 + (kbyte ^ (((r >> 2) & 1) << 5));
    return *(const bf16x8*)(region + addr);
  };
  auto COMPUTE = [&](int c){
    const char* la = (const char*)&lds[c * (BM + 256) * 64];
    const char* lb = la + BM * 128;
    #pragma unroll
    for (int ks = 0; ks < 64; ks += 32){
      int kbyte = ks * 2 + ((l >> 4) << 4);
      bf16x8 af[MI], bfv[4];
      #pragma unroll
      for (int i = 0; i < MI; i++) af[i] = LD8(la, wr * (BM / 2) + i * 16 + (l & 15), kbyte);
      #pragma unroll
      for (int j = 0; j < 4; j++)  bfv[j] = LD8(lb, wc * 64 + j * 16 + (l & 15), kbyte);
      #pragma unroll
      for (int i = 0; i < MI; i++)
        #pragma unroll
        for (int j = 0; j < 4; j++)
          acc[i][j] = MFMA(af[i], bfv[j], acc[i][j]);
    }
  };

  int NT = K >> 6;
  STAGE(0, 0);
  for (int tt = 0; tt < NT; tt++){
    if (tt + 1 < NT){
      STAGE((tt + 1) & 1, (tt + 1) * 64);
      // wait only tile tt's loads (oldest); tile tt+1's stay in flight
      if constexpr (BM == 256) asm volatile("s_waitcnt vmcnt(8)" ::: "memory");
      else                     asm volatile("s_waitcnt vmcnt(6)" ::: "memory");
    } else {
      asm volatile("s_waitcnt vmcnt(0)" ::: "memory");
    }
    __builtin_amdgcn_s_barrier();
    COMPUTE(tt & 1);
    asm volatile("s_waitcnt lgkmcnt(0)" ::: "memory");
    __builtin_amdgcn_s_barrier();             // protect buffer before re-stage
  }

  #pragma unroll
  for (int i = 0; i < MI; i++)
    #pragma unroll
    for (int j = 0; j < 4; j++)
      #pragma unroll
      for (int r = 0; r < 4; r++){
        int m = mbase + wr * (BM / 2) + i * 16 + ((l >> 4) << 2) + r;
        int n = nbase + wc * 64 + j * 16 + (l & 15);
        float v = acc[i][j][r];
        if (SPLIT){
          unsigned short bv = f2bf(v);
          if (n < 4096) ((unsigned short*)out0)[(size_t)m * 4096 + n] = bv;
          else          ((unsigned short*)out1)[(size_t)m * 4352 + (n - 4096)] = bv;
        } else {
          ((float*)out0)[(size_t)m * N + n] = v;
        }
      }
}

// ---------- dt GEMM: dtw = softplus(u_bf @ Wdt_bf^T + dt_bias), f32 accum ----------
// M=4096 (grid 32 x 128 rows), N=64 heads, K=2048. 4 waves, wave = 32 rows.
__global__ __launch_bounds__(256) void k_dtg(const unsigned short* __restrict__ A,
                                             const unsigned short* __restrict__ B,
                                             const float* __restrict__ dt_bias,
                                             float* __restrict__ dtw){
  __shared__ unsigned short sA[128 * 64];
  __shared__ unsigned short sB[64 * 64];
  const int K = 2048;
  int t = threadIdx.x, w = t >> 6, l = t & 63;
  int mbase = blockIdx.x * 128;
  const unsigned short* Ab = A + (size_t)mbase * K;
  const unsigned short* Bb = B + 8448ull * K;     // dt rows of W_in

  f32x4 acc[2][4];
  #pragma unroll
  for (int i = 0; i < 2; i++)
    #pragma unroll
    for (int j = 0; j < 4; j++) acc[i][j] = (f32x4){0.f,0.f,0.f,0.f};

  for (int kb = 0; kb < K; kb += 64){
    #pragma unroll
    for (int q = 0; q < 4; q++){
      int c = t + q * 256;
      GLOAD_LDS16(Ab + (size_t)(c >> 3) * K + kb + (c & 7) * 8, &sA[c * 8]);
    }
    #pragma unroll
    for (int q = 0; q < 2; q++){
      int c = t + q * 256;
      GLOAD_LDS16(Bb + (size_t)(c >> 3) * K + kb + (c & 7) * 8, &sB[c * 8]);
    }
    __syncthreads();
    #pragma unroll
    for (int ks = 0; ks < 64; ks += 32){
      int kk = ks + ((l >> 4) << 3);
      bf16x8 af[2], bfv[4];
      #pragma unroll
      for (int i = 0; i < 2; i++) af[i]  = *(const bf16x8*)&sA[(w * 32 + i * 16 + (l & 15)) * 64 + kk];
      #pragma unroll
      for (int j = 0; j < 4; j++) bfv[j] = *(const bf16x8*)&sB[(j * 16 + (l & 15)) * 64 + kk];
      #pragma unroll
      for (int i = 0; i < 2; i++)
        #pragma unroll
        for (int j = 0; j < 4; j++)
          acc[i][j] = MFMA(af[i], bfv[j], acc[i][j]);
    }
    __syncthreads();
  }
  #pragma unroll
  for (int i = 0; i < 2; i++)
    #pragma unroll
    for (int j = 0; j < 4; j++)
      #pragma unroll
      for (int r = 0; r < 4; r++){
        int m = mbase + w * 32 + i * 16 + ((l >> 4) << 2) + r;
        int h = j * 16 + (l & 15);
        float x = acc[i][j][r] + dt_bias[h];
        dtw[(size_t)m * 64 + h] = (x > 20.f) ? x : log1pf(expf(x));
      }
}

// ---------- causal depthwise conv (DCONV=4) + bias + silu ----------
__global__ __launch_bounds__(256) void k_conv(const unsigned short* __restrict__ xbc,
                                              const float* __restrict__ cw,
                                              const float* __restrict__ cb,
                                              unsigned short* __restrict__ xc){
  int idx = blockIdx.x * 256 + threadIdx.x;   // over 4096*544
  int tok = idx / 544;
  int ch0 = (idx - tok * 544) * 8;
  int l = tok & 2047;
  float acc[8];
  #pragma unroll
  for (int e = 0; e < 8; e++) acc[e] = cb[ch0 + e];
  #pragma unroll
  for (int d = 0; d < 4; d++){
    int ll = l - 3 + d;
    if (ll < 0) continue;
    bf16x8 v = *(const bf16x8*)(xbc + (size_t)(tok - 3 + d) * 4352 + ch0);
    #pragma unroll
    for (int e = 0; e < 8; e++)
      acc[e] += bf2f((unsigned short)v[e]) * cw[(ch0 + e) * 4 + d];
  }
  bf16x8 ov;
  #pragma unroll
  for (int e = 0; e < 8; e++){
    float a = acc[e];
    float s = a / (1.f + expf(-a));
    ov[e] = (short)f2bf(s);
  }
  *(bf16x8*)(xc + (size_t)tok * 4352 + ch0) = ov;
}

// inclusive prefix sum of 256 floats in LDS
__device__ __forceinline__ void cumsum256(float* s, int t){
  for (int off = 1; off < 256; off <<= 1){
    float v = (t >= off) ? s[t - off] : 0.f;
    __syncthreads();
    s[t] += v;
    __syncthreads();
  }
}

// ---------- per-(b,c,h) chunk states: states[p][n] = sum_j w[j] B[j][n] x[j][p] ----------
__global__ __launch_bounds__(256) void k_states(const unsigned short* __restrict__ xc,
                                                const float* __restrict__ dtw,
                                                const float* __restrict__ A_log,
                                                float* __restrict__ states,
                                                float* __restrict__ cdec){
  __shared__ unsigned short sBT[128][136];
  __shared__ unsigned short swxT[64][136];
  __shared__ float sdA[256];
  __shared__ float sdt[256];
  int t = threadIdx.x, w = t >> 6, l = t & 63;
  int h = blockIdx.x & 63, c = (blockIdx.x >> 6) & 7, b = blockIdx.x >> 9;
  int tok0 = b * 2048 + c * 256;

  float dtv = dtw[(size_t)(tok0 + t) * 64 + h];
  float Ah = -expf(A_log[h]);
  sdA[t] = dtv * Ah;
  sdt[t] = dtv;
  __syncthreads();
  cumsum256(sdA, t);
  float dA_end = sdA[255];
  if (t == 0) cdec[blockIdx.x] = expf(dA_end);

  f32x4 acc[4][2];
  #pragma unroll
  for (int i = 0; i < 4; i++){ acc[i][0] = (f32x4){0,0,0,0}; acc[i][1] = (f32x4){0,0,0,0}; }

  for (int jh = 0; jh < 2; jh++){
    #pragma unroll
    for (int q = 0; q < 8; q++){
      int id = t + q * 256;
      int jl = id >> 4, g = id & 15;
      int j = jh * 128 + jl;
      bf16x8 v = *(const bf16x8*)(xc + (size_t)(tok0 + j) * 4352 + 4096 + g * 8);
      #pragma unroll
      for (int e = 0; e < 8; e++) sBT[g * 8 + e][jl] = (unsigned short)v[e];
    }
    #pragma unroll
    for (int q = 0; q < 4; q++){
      int id = t + q * 256;
      int jl = id >> 3, g = id & 7;
      int j = jh * 128 + jl;
      float wj = expf(dA_end - sdA[j]) * sdt[j];
      bf16x8 v = *(const bf16x8*)(xc + (size_t)(tok0 + j) * 4352 + h * 64 + g * 8);
      #pragma unroll
      for (int e = 0; e < 8; e++) swxT[g * 8 + e][jl] = f2bf(bf2f((unsigned short)v[e]) * wj);
    }
    __syncthreads();
    #pragma unroll
    for (int ks = 0; ks < 4; ks++){
      int kk = ks * 32 + ((l >> 4) << 3);
      bf16x8 afr[4], bfr[2];
      #pragma unroll
      for (int pt = 0; pt < 4; pt++) afr[pt] = *(const bf16x8*)&swxT[pt * 16 + (l & 15)][kk];
      #pragma unroll
      for (int nt = 0; nt < 2; nt++) bfr[nt] = *(const bf16x8*)&sBT[(w * 2 + nt) * 16 + (l & 15)][kk];
      #pragma unroll
      for (int pt = 0; pt < 4; pt++)
        #pragma unroll
        for (int nt = 0; nt < 2; nt++)
          acc[pt][nt] = MFMA(afr[pt], bfr[nt], acc[pt][nt]);
    }
    __syncthreads();
  }
  float* sp = states + (size_t)blockIdx.x * 8192;
  #pragma unroll
  for (int pt = 0; pt < 4; pt++)
    #pragma unroll
    for (int nt = 0; nt < 2; nt++)
      #pragma unroll
      for (int r = 0; r < 4; r++){
        int p = pt * 16 + ((l >> 4) << 2) + r;
        int n = (w * 2 + nt) * 16 + (l & 15);
        sp[p * 128 + n] = acc[pt][nt][r];
      }
}

// ---------- sequential scan over 8 chunks per (b,h,quarter): 512 blocks ----------
__global__ __launch_bounds__(256) void k_scan(const float* __restrict__ states,
                                              const float* __restrict__ cdec,
                                              unsigned short* __restrict__ hprev){
  int q = blockIdx.x & 3, bh = blockIdx.x >> 2;
  int b = bh >> 6, h = bh & 63;
  int t = threadIdx.x;
  float carry[8];
  #pragma unroll
  for (int i = 0; i < 8; i++) carry[i] = 0.f;
  for (int c = 0; c < 8; c++){
    int bch = (b * 8 + c) * 64 + h;
    size_t base = (size_t)bch * 8192 + q * 2048;
    float d = cdec[bch];
    #pragma unroll
    for (int i = 0; i < 8; i++){
      int e = t + i * 256;
      hprev[base + e] = f2bf(carry[i]);
      carry[i] = carry[i] * d + states[base + e];
    }
  }
}

// ---------- per-(b,c,h): y = (scores@x) + (C*expf)@h_prev^T + Dp*x ----------
__global__ __launch_bounds__(256) void k_y(const unsigned short* __restrict__ xc,
                                           const float* __restrict__ dtw,
                                           const float* __restrict__ A_log,
                                           const unsigned short* __restrict__ hprev,
                                           const float* __restrict__ Dp,
                                           unsigned short* __restrict__ y){
  __shared__ unsigned short sxT[64][264];
  __shared__ unsigned short sS[4][64][40];
  __shared__ float sdA[256];
  __shared__ float sdt[256];
  int t = threadIdx.x, w = t >> 6, l = t & 63;
  int h = blockIdx.x & 63, c = (blockIdx.x >> 6) & 7, b = blockIdx.x >> 9;
  int tok0 = b * 2048 + c * 256;
  int ib = w * 64;

  float dtv = dtw[(size_t)(tok0 + t) * 64 + h];
  float Ah = -expf(A_log[h]);
  sdA[t] = dtv * Ah;
  sdt[t] = dtv;
  __syncthreads();
  cumsum256(sdA, t);

  #pragma unroll
  for (int q = 0; q < 8; q++){
    int id = t + q * 256;
    int j = id >> 3, g = id & 7;
    bf16x8 v = *(const bf16x8*)(xc + (size_t)(tok0 + j) * 4352 + h * 64 + g * 8);
    #pragma unroll
    for (int e = 0; e < 8; e++) sxT[g * 8 + e][j] = (unsigned short)v[e];
  }
  __syncthreads();

  bf16x8 cfr[4][4];
  #pragma unroll
  for (int it = 0; it < 4; it++)
    #pragma unroll
    for (int kn = 0; kn < 4; kn++){
      int i = ib + it * 16 + (l & 15);
      int n = kn * 32 + ((l >> 4) << 3);
      cfr[it][kn] = *(const bf16x8*)(xc + (size_t)(tok0 + i) * 4352 + 4224 + n);
    }

  f32x4 acc[4][4];
  #pragma unroll
  for (int i = 0; i < 4; i++)
    #pragma unroll
    for (int j = 0; j < 4; j++) acc[i][j] = (f32x4){0,0,0,0};

  for (int jt = 0; jt < 8; jt++){
    f32x4 cb[4][2];
    #pragma unroll
    for (int i = 0; i < 4; i++){ cb[i][0] = (f32x4){0,0,0,0}; cb[i][1] = (f32x4){0,0,0,0}; }
    #pragma unroll
    for (int kn = 0; kn < 4; kn++){
      bf16x8 bfr[2];
      #pragma unroll
      for (int js = 0; js < 2; js++){
        int j = jt * 32 + js * 16 + (l & 15);
        int n = kn * 32 + ((l >> 4) << 3);
        bfr[js] = *(const bf16x8*)(xc + (size_t)(tok0 + j) * 4352 + 4096 + n);
      }
      #pragma unroll
      for (int it = 0; it < 4; it++)
        #pragma unroll
        for (int js = 0; js < 2; js++)
          cb[it][js] = MFMA(cfr[it][kn], bfr[js], cb[it][js]);
    }
    #pragma unroll
    for (int it = 0; it < 4; it++)
      #pragma unroll
      for (int js = 0; js < 2; js++)
        #pragma unroll
        for (int r = 0; r < 4; r++){
          int il = it * 16 + ((l >> 4) << 2) + r;
          int i = ib + il;
          int j = jt * 32 + js * 16 + (l & 15);
          float v = (i >= j) ? cb[it][js][r] * expf(sdA[i] - sdA[j]) * sdt[j] : 0.f;
          sS[w][il][js * 16 + (l & 15)] = f2bf(v);
        }
    int kk = ((l >> 4) << 3);
    bf16x8 sfr[4], xfr[4];
    #pragma unroll
    for (int it = 0; it < 4; it++) sfr[it] = *(const bf16x8*)&sS[w][it * 16 + (l & 15)][kk];
    #pragma unroll
    for (int pt = 0; pt < 4; pt++) xfr[pt] = *(const bf16x8*)&sxT[pt * 16 + (l & 15)][jt * 32 + kk];
    #pragma unroll
    for (int it = 0; it < 4; it++)
      #pragma unroll
      for (int pt = 0; pt < 4; pt++)
        acc[it][pt] = MFMA(sfr[it], xfr[pt], acc[it][pt]);
  }

  const unsigned short* hp = hprev + (size_t)blockIdx.x * 8192;
  float esc[4];
  #pragma unroll
  for (int it = 0; it < 4; it++) esc[it] = expf(sdA[ib + it * 16 + (l & 15)]);
  #pragma unroll
  for (int kn = 0; kn < 4; kn++){
    bf16x8 hfr[4];
    #pragma unroll
    for (int pt = 0; pt < 4; pt++){
      int p = pt * 16 + (l & 15);
      int n = kn * 32 + ((l >> 4) << 3);
      hfr[pt] = *(const bf16x8*)(hp + p * 128 + n);
    }
    #pragma unroll
    for (int it = 0; it < 4; it++){
      bf16x8 afv;
      #pragma unroll
      for (int e = 0; e < 8; e++)
        afv[e] = (short)f2bf(bf2f((unsigned short)cfr[it][kn][e]) * esc[it]);
      #pragma unroll
      for (int pt = 0; pt < 4; pt++)
        acc[it][pt] = MFMA(afv, hfr[pt], acc[it][pt]);
    }
  }

  float dph = Dp[h];
  #pragma unroll
  for (int it = 0; it < 4; it++)
    #pragma unroll
    for (int pt = 0; pt < 4; pt++)
      #pragma unroll
      for (int r = 0; r < 4; r++){
        int i = ib + it * 16 + ((l >> 4) << 2) + r;
        int p = pt * 16 + (l & 15);
        float xv = bf2f(sxT[p][i]);
        float v = acc[it][pt][r] + dph * xv;
        y[(size_t)(tok0 + i) * 4096 + h * 64 + p] = f2bf(v);
      }
}

// ---------- gate with silu(z), RMS-norm, * norm_w -> bf16 ----------
__global__ __launch_bounds__(256) void k_norm(const unsigned short* __restrict__ y,
                                              const unsigned short* __restrict__ zbuf,
                                              const float* __restrict__ norm_w,
                                              unsigned short* __restrict__ yn){
  int tok = blockIdx.x, t = threadIdx.x, w = t >> 6, l = t & 63;
  float vals[16];
  float ss = 0.f;
  #pragma unroll
  for (int q = 0; q < 2; q++){
    int col = q * 2048 + t * 8;
    bf16x8 yv = *(const bf16x8*)(y    + (size_t)tok * 4096 + col);
    bf16x8 zv = *(const bf16x8*)(zbuf + (size_t)tok * 4096 + col);
    #pragma unroll
    for (int e = 0; e < 8; e++){
      float yy = bf2f((unsigned short)yv[e]);
      float zz = bf2f((unsigned short)zv[e]);
      float g = yy * (zz / (1.f + expf(-zz)));
      vals[q * 8 + e] = g;
      ss += g * g;
    }
  }
  #pragma unroll
  for (int off = 32; off >= 1; off >>= 1) ss += __shfl_xor(ss, off, 64);
  __shared__ float red[4];
  if (l == 0) red[w] = ss;
  __syncthreads();
  float total = red[0] + red[1] + red[2] + red[3];
  float scale = rsqrtf(total * (1.f / 4096.f) + 1e-5f);
  #pragma unroll
  for (int q = 0; q < 2; q++){
    int col = q * 2048 + t * 8;
    bf16x8 ov;
    #pragma unroll
    for (int e = 0; e < 8; e++) ov[e] = (short)f2bf(vals[q * 8 + e] * scale * norm_w[col + e]);
    *(bf16x8*)(yn + (size_t)tok * 4096 + col) = ov;
  }
}

extern "C" void kernel_launch(void* const* d_in, const int* in_sizes, int n_in,
                              void* d_out, int out_size, void* d_ws, size_t ws_size,
                              hipStream_t stream) {
  const float* u       = (const float*)d_in[0];
  const float* W_in    = (const float*)d_in[1];
  const float* conv_w  = (const float*)d_in[2];
  const float* conv_b  = (const float*)d_in[3];
  const float* dt_bias = (const float*)d_in[4];
  const float* A_log   = (const float*)d_in[5];
  const float* Dp      = (const float*)d_in[6];
  const float* norm_w  = (const float*)d_in[7];
  const float* W_out   = (const float*)d_in[8];

  char* ws = (char*)d_ws;
  size_t off = 0;
  auto nxt = [&](size_t bytes) -> char* {
    char* r = ws + off;
    off += (bytes + 255) & ~(size_t)255;
    return r;
  };
  char* RZ = nxt(4096ull * 4096 * 2);   // zbuf -> wout_bf
  char* RX = nxt(4096ull * 4352 * 2);   // xbc -> states(f32) -> ybuf
  char* RC = nxt(4096ull * 4352 * 2);   // win_bf -> xc -> ynbuf
  char* RH = nxt(1024ull * 8192 * 2);   // u_bf -> hprev
  float* dtw  = (float*)nxt(4096ull * 64 * 4);
  float* cdec = (float*)nxt(1024ull * 4);
  size_t need = off;
  (void)in_sizes; (void)n_in; (void)out_size;
  if (ws_size < need) return;

  unsigned short* zbuf    = (unsigned short*)RZ;
  unsigned short* wout_bf = (unsigned short*)RZ;   // after k_norm
  unsigned short* xbc     = (unsigned short*)RX;
  float*          states  = (float*)RX;
  unsigned short* ybuf    = (unsigned short*)RX;
  unsigned short* win_bf  = (unsigned short*)RC;
  unsigned short* xc      = (unsigned short*)RC;
  unsigned short* ynbuf   = (unsigned short*)RC;
  unsigned short* u_bf    = (unsigned short*)RH;
  unsigned short* hprev   = (unsigned short*)RH;

  k_f2bf<<<8192,  256, 0, stream>>>(u,    u_bf,   4096 * 2048);
  k_f2bf<<<17024, 256, 0, stream>>>(W_in, win_bf, 8512 * 2048);
  k_dtg<<<32, 256, 0, stream>>>(u_bf, win_bf, dt_bias, dtw);
  // in-proj: M=4096, N=8448 (dt cols excluded), K=2048; 256x256 tiles, grid 33x16
  k_gcnt<256,1><<<dim3(33, 16), 512, 0, stream>>>(u_bf, win_bf, zbuf, xbc, 8448, 2048);
  k_conv<<<8704, 256, 0, stream>>>(xbc, conv_w, conv_b, xc);
  k_states<<<1024, 256, 0, stream>>>(xc, dtw, A_log, states, cdec);
  k_scan<<<512, 256, 0, stream>>>(states, cdec, hprev);
  k_y<<<1024, 256, 0, stream>>>(xc, dtw, A_log, hprev, Dp, ybuf);
  k_norm<<<4096, 256, 0, stream>>>(ybuf, zbuf, norm_w, ynbuf);
  k_f2bf<<<8192, 256, 0, stream>>>(W_out, wout_bf, 2048 * 4096);
  // out-proj: M=4096, N=2048, K=4096; 128x256 tiles, grid 8x32 (256 blocks)
  k_gcnt<128,0><<<dim3(8, 32), 512, 0, stream>>>(ynbuf, wout_bf, d_out, nullptr, 2048, 4096);
}

// Round 7
// 620.111 us; speedup vs baseline: 1.4368x; 1.0231x over previous
//
#include <hip/hip_runtime.h>
#include <hip/hip_bf16.h>

// ---------------- Mamba2 block (B=2, L=2048, D_MODEL=2048, D_INNER=4096,
// NH=64, HP=64, DS=128, G=1, DCONV=4, CHUNK=256) ----------------
// Round 7: fix T2 swizzle to full 3-bit ((row&7)<<4) on both sides (R6 used
// 1 bit -> residual 4-way conflicts). k_y: skip fully-masked j-tiles
// (per-wave triangular bound). Everything else unchanged from R6.

typedef __attribute__((ext_vector_type(8))) short bf16x8;
typedef __attribute__((ext_vector_type(4))) float f32x4;
typedef __attribute__((ext_vector_type(4))) float float4v;

#define MFMA(a,b,c) __builtin_amdgcn_mfma_f32_16x16x32_bf16((a),(b),(c),0,0,0)

#define GLOAD_LDS16(gp, lp) \
  __builtin_amdgcn_global_load_lds((const __attribute__((address_space(1))) void*)(gp), \
                                   (__attribute__((address_space(3))) void*)(lp), 16, 0, 0)

__device__ __forceinline__ float bf2f(unsigned short u){
  union { unsigned int i; float f; } v; v.i = ((unsigned int)u) << 16; return v.f;
}
__device__ __forceinline__ unsigned short f2bf(float f){
  union { float f; unsigned int i; } v; v.f = f;
  unsigned int x = v.i;
  return (unsigned short)((x + 0x7fffu + ((x >> 16) & 1u)) >> 16);
}

// ---------- f32 -> bf16 (vectorized cast) ----------
__global__ __launch_bounds__(256) void k_f2bf(const float* __restrict__ in,
                                              unsigned short* __restrict__ out, int n){
  int i = (blockIdx.x * 256 + threadIdx.x) * 4;
  if (i >= n) return;
  float4v v = *(const float4v*)(in + i);
  union { unsigned short u[4]; unsigned long long ll; } o;
  o.u[0] = f2bf(v.x); o.u[1] = f2bf(v.y); o.u[2] = f2bf(v.z); o.u[3] = f2bf(v.w);
  *(unsigned long long*)(out + i) = o.ll;
}

// ---------- counted-vmcnt GEMM: C[m][n] = sum_k A[m][k]*B[n][k] ----------
// BN=256 fixed, BK=64, 512 threads (8 waves, 2M x 4N).
// BM=256 (SPLIT=1: bf16 split store z/xbc) or BM=128 (SPLIT=0: f32 out).
// T2 swizzle: byte ^= ((row&7)<<4) — LDS linear dest, inverse-swizzled global
// src, swizzled ds_read (involution, both-sides).
template<int BM, int SPLIT>
__global__ __launch_bounds__(512, 2) void k_gcnt(const unsigned short* __restrict__ A,
                                                 const unsigned short* __restrict__ B,
                                                 void* __restrict__ out0,
                                                 void* __restrict__ out1,
                                                 int N, int K){
  constexpr int MI = BM / 32;                 // A frags per wave (M dir)
  __shared__ unsigned short lds[2 * (BM + 256) * 64];
  int t = threadIdx.x, wid = t >> 6, l = t & 63;
  int wr = wid >> 2, wc = wid & 3;            // wave grid 2(M) x 4(N)
  // bijective XCD swizzle (grid product divisible by 8)
  int nbx = gridDim.x;
  int bid = blockIdx.y * nbx + blockIdx.x;
  int cpx = (nbx * gridDim.y) >> 3;
  int sbid = (bid & 7) * cpx + (bid >> 3);
  int bx = sbid % nbx, by = sbid / nbx;
  int mbase = by * BM, nbase = bx * 256;

  const unsigned short* Ab = A + (size_t)mbase * K;
  const unsigned short* Bb = B + (size_t)nbase * K;

  f32x4 acc[MI][4];
  #pragma unroll
  for (int i = 0; i < MI; i++)
    #pragma unroll
    for (int j = 0; j < 4; j++) acc[i][j] = (f32x4){0.f,0.f,0.f,0.f};

  // stage one K-tile into buffer c; LDS dest linear, global src inverse-swizzled
  auto STAGE = [&](int c, int kb){
    char* la = (char*)&lds[c * (BM + 256) * 64];
    char* lb = la + BM * 128;
    #pragma unroll
    for (int q = 0; q < BM / 64; q++){        // A: BM*8 chunks of 16B
      int o = (t + q * 512) * 16;
      int bs = o ^ (((o >> 7) & 7) << 4);     // row bits 7..9 -> byte bits 4..6
      int r = bs >> 7, cb = bs & 127;
      GLOAD_LDS16((const char*)Ab + (size_t)r * (K * 2) + (size_t)kb * 2 + cb, la + o);
    }
    #pragma unroll
    for (int q = 0; q < 4; q++){              // B: 2048 chunks of 16B
      int o = (t + q * 512) * 16;
      int bs = o ^ (((o >> 7) & 7) << 4);
      int r = bs >> 7, cb = bs & 127;
      GLOAD_LDS16((const char*)Bb + (size_t)r * (K * 2) + (size_t)kb * 2 + cb, lb + o);
    }
  };
  // swizzled fragment read: region-local row r, byte-col kbyte (16B aligned)
  auto LD8 = [&](const char* region, int r, int kbyte) -> bf16x8 {
    int addr = r * 128 + (kbyte ^ ((r & 7) << 4));
    return *(const bf16x8*)(region + addr);
  };
  auto COMPUTE = [&](int c){
    const char* la = (const char*)&lds[c * (BM + 256) * 64];
    const char* lb = la + BM * 128;
    #pragma unroll
    for (int ks = 0; ks < 64; ks += 32){
      int kbyte = ks * 2 + ((l >> 4) << 4);
      bf16x8 af[MI], bfv[4];
      #pragma unroll
      for (int i = 0; i < MI; i++) af[i] = LD8(la, wr * (BM / 2) + i * 16 + (l & 15), kbyte);
      #pragma unroll
      for (int j = 0; j < 4; j++)  bfv[j] = LD8(lb, wc * 64 + j * 16 + (l & 15), kbyte);
      #pragma unroll
      for (int i = 0; i < MI; i++)
        #pragma unroll
        for (int j = 0; j < 4; j++)
          acc[i][j] = MFMA(af[i], bfv[j], acc[i][j]);
    }
  };

  int NT = K >> 6;
  STAGE(0, 0);
  for (int tt = 0; tt < NT; tt++){
    if (tt + 1 < NT){
      STAGE((tt + 1) & 1, (tt + 1) * 64);
      // wait only tile tt's loads (oldest); tile tt+1's stay in flight
      if constexpr (BM == 256) asm volatile("s_waitcnt vmcnt(8)" ::: "memory");
      else                     asm volatile("s_waitcnt vmcnt(6)" ::: "memory");
    } else {
      asm volatile("s_waitcnt vmcnt(0)" ::: "memory");
    }
    __builtin_amdgcn_s_barrier();
    COMPUTE(tt & 1);
    asm volatile("s_waitcnt lgkmcnt(0)" ::: "memory");
    __builtin_amdgcn_s_barrier();             // protect buffer before re-stage
  }

  #pragma unroll
  for (int i = 0; i < MI; i++)
    #pragma unroll
    for (int j = 0; j < 4; j++)
      #pragma unroll
      for (int r = 0; r < 4; r++){
        int m = mbase + wr * (BM / 2) + i * 16 + ((l >> 4) << 2) + r;
        int n = nbase + wc * 64 + j * 16 + (l & 15);
        float v = acc[i][j][r];
        if (SPLIT){
          unsigned short bv = f2bf(v);
          if (n < 4096) ((unsigned short*)out0)[(size_t)m * 4096 + n] = bv;
          else          ((unsigned short*)out1)[(size_t)m * 4352 + (n - 4096)] = bv;
        } else {
          ((float*)out0)[(size_t)m * N + n] = v;
        }
      }
}

// ---------- dt GEMM: dtw = softplus(u_bf @ Wdt_bf^T + dt_bias), f32 accum ----------
__global__ __launch_bounds__(256) void k_dtg(const unsigned short* __restrict__ A,
                                             const unsigned short* __restrict__ B,
                                             const float* __restrict__ dt_bias,
                                             float* __restrict__ dtw){
  __shared__ unsigned short sA[128 * 64];
  __shared__ unsigned short sB[64 * 64];
  const int K = 2048;
  int t = threadIdx.x, w = t >> 6, l = t & 63;
  int mbase = blockIdx.x * 128;
  const unsigned short* Ab = A + (size_t)mbase * K;
  const unsigned short* Bb = B + 8448ull * K;     // dt rows of W_in

  f32x4 acc[2][4];
  #pragma unroll
  for (int i = 0; i < 2; i++)
    #pragma unroll
    for (int j = 0; j < 4; j++) acc[i][j] = (f32x4){0.f,0.f,0.f,0.f};

  for (int kb = 0; kb < K; kb += 64){
    #pragma unroll
    for (int q = 0; q < 4; q++){
      int c = t + q * 256;
      GLOAD_LDS16(Ab + (size_t)(c >> 3) * K + kb + (c & 7) * 8, &sA[c * 8]);
    }
    #pragma unroll
    for (int q = 0; q < 2; q++){
      int c = t + q * 256;
      GLOAD_LDS16(Bb + (size_t)(c >> 3) * K + kb + (c & 7) * 8, &sB[c * 8]);
    }
    __syncthreads();
    #pragma unroll
    for (int ks = 0; ks < 64; ks += 32){
      int kk = ks + ((l >> 4) << 3);
      bf16x8 af[2], bfv[4];
      #pragma unroll
      for (int i = 0; i < 2; i++) af[i]  = *(const bf16x8*)&sA[(w * 32 + i * 16 + (l & 15)) * 64 + kk];
      #pragma unroll
      for (int j = 0; j < 4; j++) bfv[j] = *(const bf16x8*)&sB[(j * 16 + (l & 15)) * 64 + kk];
      #pragma unroll
      for (int i = 0; i < 2; i++)
        #pragma unroll
        for (int j = 0; j < 4; j++)
          acc[i][j] = MFMA(af[i], bfv[j], acc[i][j]);
    }
    __syncthreads();
  }
  #pragma unroll
  for (int i = 0; i < 2; i++)
    #pragma unroll
    for (int j = 0; j < 4; j++)
      #pragma unroll
      for (int r = 0; r < 4; r++){
        int m = mbase + w * 32 + i * 16 + ((l >> 4) << 2) + r;
        int h = j * 16 + (l & 15);
        float x = acc[i][j][r] + dt_bias[h];
        dtw[(size_t)m * 64 + h] = (x > 20.f) ? x : log1pf(expf(x));
      }
}

// ---------- causal depthwise conv (DCONV=4) + bias + silu ----------
__global__ __launch_bounds__(256) void k_conv(const unsigned short* __restrict__ xbc,
                                              const float* __restrict__ cw,
                                              const float* __restrict__ cb,
                                              unsigned short* __restrict__ xc){
  int idx = blockIdx.x * 256 + threadIdx.x;   // over 4096*544
  int tok = idx / 544;
  int ch0 = (idx - tok * 544) * 8;
  int l = tok & 2047;
  float acc[8];
  #pragma unroll
  for (int e = 0; e < 8; e++) acc[e] = cb[ch0 + e];
  #pragma unroll
  for (int d = 0; d < 4; d++){
    int ll = l - 3 + d;
    if (ll < 0) continue;
    bf16x8 v = *(const bf16x8*)(xbc + (size_t)(tok - 3 + d) * 4352 + ch0);
    #pragma unroll
    for (int e = 0; e < 8; e++)
      acc[e] += bf2f((unsigned short)v[e]) * cw[(ch0 + e) * 4 + d];
  }
  bf16x8 ov;
  #pragma unroll
  for (int e = 0; e < 8; e++){
    float a = acc[e];
    float s = a / (1.f + expf(-a));
    ov[e] = (short)f2bf(s);
  }
  *(bf16x8*)(xc + (size_t)tok * 4352 + ch0) = ov;
}

// inclusive prefix sum of 256 floats in LDS
__device__ __forceinline__ void cumsum256(float* s, int t){
  for (int off = 1; off < 256; off <<= 1){
    float v = (t >= off) ? s[t - off] : 0.f;
    __syncthreads();
    s[t] += v;
    __syncthreads();
  }
}

// ---------- per-(b,c,h) chunk states: states[p][n] = sum_j w[j] B[j][n] x[j][p] ----------
__global__ __launch_bounds__(256) void k_states(const unsigned short* __restrict__ xc,
                                                const float* __restrict__ dtw,
                                                const float* __restrict__ A_log,
                                                float* __restrict__ states,
                                                float* __restrict__ cdec){
  __shared__ unsigned short sBT[128][136];
  __shared__ unsigned short swxT[64][136];
  __shared__ float sdA[256];
  __shared__ float sdt[256];
  int t = threadIdx.x, w = t >> 6, l = t & 63;
  int h = blockIdx.x & 63, c = (blockIdx.x >> 6) & 7, b = blockIdx.x >> 9;
  int tok0 = b * 2048 + c * 256;

  float dtv = dtw[(size_t)(tok0 + t) * 64 + h];
  float Ah = -expf(A_log[h]);
  sdA[t] = dtv * Ah;
  sdt[t] = dtv;
  __syncthreads();
  cumsum256(sdA, t);
  float dA_end = sdA[255];
  if (t == 0) cdec[blockIdx.x] = expf(dA_end);

  f32x4 acc[4][2];
  #pragma unroll
  for (int i = 0; i < 4; i++){ acc[i][0] = (f32x4){0,0,0,0}; acc[i][1] = (f32x4){0,0,0,0}; }

  for (int jh = 0; jh < 2; jh++){
    #pragma unroll
    for (int q = 0; q < 8; q++){
      int id = t + q * 256;
      int jl = id >> 4, g = id & 15;
      int j = jh * 128 + jl;
      bf16x8 v = *(const bf16x8*)(xc + (size_t)(tok0 + j) * 4352 + 4096 + g * 8);
      #pragma unroll
      for (int e = 0; e < 8; e++) sBT[g * 8 + e][jl] = (unsigned short)v[e];
    }
    #pragma unroll
    for (int q = 0; q < 4; q++){
      int id = t + q * 256;
      int jl = id >> 3, g = id & 7;
      int j = jh * 128 + jl;
      float wj = expf(dA_end - sdA[j]) * sdt[j];
      bf16x8 v = *(const bf16x8*)(xc + (size_t)(tok0 + j) * 4352 + h * 64 + g * 8);
      #pragma unroll
      for (int e = 0; e < 8; e++) swxT[g * 8 + e][jl] = f2bf(bf2f((unsigned short)v[e]) * wj);
    }
    __syncthreads();
    #pragma unroll
    for (int ks = 0; ks < 4; ks++){
      int kk = ks * 32 + ((l >> 4) << 3);
      bf16x8 afr[4], bfr[2];
      #pragma unroll
      for (int pt = 0; pt < 4; pt++) afr[pt] = *(const bf16x8*)&swxT[pt * 16 + (l & 15)][kk];
      #pragma unroll
      for (int nt = 0; nt < 2; nt++) bfr[nt] = *(const bf16x8*)&sBT[(w * 2 + nt) * 16 + (l & 15)][kk];
      #pragma unroll
      for (int pt = 0; pt < 4; pt++)
        #pragma unroll
        for (int nt = 0; nt < 2; nt++)
          acc[pt][nt] = MFMA(afr[pt], bfr[nt], acc[pt][nt]);
    }
    __syncthreads();
  }
  float* sp = states + (size_t)blockIdx.x * 8192;
  #pragma unroll
  for (int pt = 0; pt < 4; pt++)
    #pragma unroll
    for (int nt = 0; nt < 2; nt++)
      #pragma unroll
      for (int r = 0; r < 4; r++){
        int p = pt * 16 + ((l >> 4) << 2) + r;
        int n = (w * 2 + nt) * 16 + (l & 15);
        sp[p * 128 + n] = acc[pt][nt][r];
      }
}

// ---------- sequential scan over 8 chunks per (b,h,quarter): 512 blocks ----------
__global__ __launch_bounds__(256) void k_scan(const float* __restrict__ states,
                                              const float* __restrict__ cdec,
                                              unsigned short* __restrict__ hprev){
  int q = blockIdx.x & 3, bh = blockIdx.x >> 2;
  int b = bh >> 6, h = bh & 63;
  int t = threadIdx.x;
  float carry[8];
  #pragma unroll
  for (int i = 0; i < 8; i++) carry[i] = 0.f;
  for (int c = 0; c < 8; c++){
    int bch = (b * 8 + c) * 64 + h;
    size_t base = (size_t)bch * 8192 + q * 2048;
    float d = cdec[bch];
    #pragma unroll
    for (int i = 0; i < 8; i++){
      int e = t + i * 256;
      hprev[base + e] = f2bf(carry[i]);
      carry[i] = carry[i] * d + states[base + e];
    }
  }
}

// ---------- per-(b,c,h): y = (scores@x) + (C*expf)@h_prev^T + Dp*x ----------
__global__ __launch_bounds__(256) void k_y(const unsigned short* __restrict__ xc,
                                           const float* __restrict__ dtw,
                                           const float* __restrict__ A_log,
                                           const unsigned short* __restrict__ hprev,
                                           const float* __restrict__ Dp,
                                           unsigned short* __restrict__ y){
  __shared__ unsigned short sxT[64][264];
  __shared__ unsigned short sS[4][64][40];
  __shared__ float sdA[256];
  __shared__ float sdt[256];
  int t = threadIdx.x, w = t >> 6, l = t & 63;
  int h = blockIdx.x & 63, c = (blockIdx.x >> 6) & 7, b = blockIdx.x >> 9;
  int tok0 = b * 2048 + c * 256;
  int ib = w * 64;

  float dtv = dtw[(size_t)(tok0 + t) * 64 + h];
  float Ah = -expf(A_log[h]);
  sdA[t] = dtv * Ah;
  sdt[t] = dtv;
  __syncthreads();
  cumsum256(sdA, t);

  #pragma unroll
  for (int q = 0; q < 8; q++){
    int id = t + q * 256;
    int j = id >> 3, g = id & 7;
    bf16x8 v = *(const bf16x8*)(xc + (size_t)(tok0 + j) * 4352 + h * 64 + g * 8);
    #pragma unroll
    for (int e = 0; e < 8; e++) sxT[g * 8 + e][j] = (unsigned short)v[e];
  }
  __syncthreads();

  bf16x8 cfr[4][4];
  #pragma unroll
  for (int it = 0; it < 4; it++)
    #pragma unroll
    for (int kn = 0; kn < 4; kn++){
      int i = ib + it * 16 + (l & 15);
      int n = kn * 32 + ((l >> 4) << 3);
      cfr[it][kn] = *(const bf16x8*)(xc + (size_t)(tok0 + i) * 4352 + 4224 + n);
    }

  f32x4 acc[4][4];
  #pragma unroll
  for (int i = 0; i < 4; i++)
    #pragma unroll
    for (int j = 0; j < 4; j++) acc[i][j] = (f32x4){0,0,0,0};

  // triangular skip: j-tiles with jt*32 > ib+63 are fully masked for this wave
  int njt = (ib >> 5) + 2;
  for (int jt = 0; jt < njt; jt++){
    f32x4 cb[4][2];
    #pragma unroll
    for (int i = 0; i < 4; i++){ cb[i][0] = (f32x4){0,0,0,0}; cb[i][1] = (f32x4){0,0,0,0}; }
    #pragma unroll
    for (int kn = 0; kn < 4; kn++){
      bf16x8 bfr[2];
      #pragma unroll
      for (int js = 0; js < 2; js++){
        int j = jt * 32 + js * 16 + (l & 15);
        int n = kn * 32 + ((l >> 4) << 3);
        bfr[js] = *(const bf16x8*)(xc + (size_t)(tok0 + j) * 4352 + 4096 + n);
      }
      #pragma unroll
      for (int it = 0; it < 4; it++)
        #pragma unroll
        for (int js = 0; js < 2; js++)
          cb[it][js] = MFMA(cfr[it][kn], bfr[js], cb[it][js]);
    }
    #pragma unroll
    for (int it = 0; it < 4; it++)
      #pragma unroll
      for (int js = 0; js < 2; js++)
        #pragma unroll
        for (int r = 0; r < 4; r++){
          int il = it * 16 + ((l >> 4) << 2) + r;
          int i = ib + il;
          int j = jt * 32 + js * 16 + (l & 15);
          float v = (i >= j) ? cb[it][js][r] * expf(sdA[i] - sdA[j]) * sdt[j] : 0.f;
          sS[w][il][js * 16 + (l & 15)] = f2bf(v);
        }
    int kk = ((l >> 4) << 3);
    bf16x8 sfr[4], xfr[4];
    #pragma unroll
    for (int it = 0; it < 4; it++) sfr[it] = *(const bf16x8*)&sS[w][it * 16 + (l & 15)][kk];
    #pragma unroll
    for (int pt = 0; pt < 4; pt++) xfr[pt] = *(const bf16x8*)&sxT[pt * 16 + (l & 15)][jt * 32 + kk];
    #pragma unroll
    for (int it = 0; it < 4; it++)
      #pragma unroll
      for (int pt = 0; pt < 4; pt++)
        acc[it][pt] = MFMA(sfr[it], xfr[pt], acc[it][pt]);
  }

  const unsigned short* hp = hprev + (size_t)blockIdx.x * 8192;
  float esc[4];
  #pragma unroll
  for (int it = 0; it < 4; it++) esc[it] = expf(sdA[ib + it * 16 + (l & 15)]);
  #pragma unroll
  for (int kn = 0; kn < 4; kn++){
    bf16x8 hfr[4];
    #pragma unroll
    for (int pt = 0; pt < 4; pt++){
      int p = pt * 16 + (l & 15);
      int n = kn * 32 + ((l >> 4) << 3);
      hfr[pt] = *(const bf16x8*)(hp + p * 128 + n);
    }
    #pragma unroll
    for (int it = 0; it < 4; it++){
      bf16x8 afv;
      #pragma unroll
      for (int e = 0; e < 8; e++)
        afv[e] = (short)f2bf(bf2f((unsigned short)cfr[it][kn][e]) * esc[it]);
      #pragma unroll
      for (int pt = 0; pt < 4; pt++)
        acc[it][pt] = MFMA(afv, hfr[pt], acc[it][pt]);
    }
  }

  float dph = Dp[h];
  #pragma unroll
  for (int it = 0; it < 4; it++)
    #pragma unroll
    for (int pt = 0; pt < 4; pt++)
      #pragma unroll
      for (int r = 0; r < 4; r++){
        int i = ib + it * 16 + ((l >> 4) << 2) + r;
        int p = pt * 16 + (l & 15);
        float xv = bf2f(sxT[p][i]);
        float v = acc[it][pt][r] + dph * xv;
        y[(size_t)(tok0 + i) * 4096 + h * 64 + p] = f2bf(v);
      }
}

// ---------- gate with silu(z), RMS-norm, * norm_w -> bf16 ----------
__global__ __launch_bounds__(256) void k_norm(const unsigned short* __restrict__ y,
                                              const unsigned short* __restrict__ zbuf,
                                              const float* __restrict__ norm_w,
                                              unsigned short* __restrict__ yn){
  int tok = blockIdx.x, t = threadIdx.x, w = t >> 6, l = t & 63;
  float vals[16];
  float ss = 0.f;
  #pragma unroll
  for (int q = 0; q < 2; q++){
    int col = q * 2048 + t * 8;
    bf16x8 yv = *(const bf16x8*)(y    + (size_t)tok * 4096 + col);
    bf16x8 zv = *(const bf16x8*)(zbuf + (size_t)tok * 4096 + col);
    #pragma unroll
    for (int e = 0; e < 8; e++){
      float yy = bf2f((unsigned short)yv[e]);
      float zz = bf2f((unsigned short)zv[e]);
      float g = yy * (zz / (1.f + expf(-zz)));
      vals[q * 8 + e] = g;
      ss += g * g;
    }
  }
  #pragma unroll
  for (int off = 32; off >= 1; off >>= 1) ss += __shfl_xor(ss, off, 64);
  __shared__ float red[4];
  if (l == 0) red[w] = ss;
  __syncthreads();
  float total = red[0] + red[1] + red[2] + red[3];
  float scale = rsqrtf(total * (1.f / 4096.f) + 1e-5f);
  #pragma unroll
  for (int q = 0; q < 2; q++){
    int col = q * 2048 + t * 8;
    bf16x8 ov;
    #pragma unroll
    for (int e = 0; e < 8; e++) ov[e] = (short)f2bf(vals[q * 8 + e] * scale * norm_w[col + e]);
    *(bf16x8*)(yn + (size_t)tok * 4096 + col) = ov;
  }
}

extern "C" void kernel_launch(void* const* d_in, const int* in_sizes, int n_in,
                              void* d_out, int out_size, void* d_ws, size_t ws_size,
                              hipStream_t stream) {
  const float* u       = (const float*)d_in[0];
  const float* W_in    = (const float*)d_in[1];
  const float* conv_w  = (const float*)d_in[2];
  const float* conv_b  = (const float*)d_in[3];
  const float* dt_bias = (const float*)d_in[4];
  const float* A_log   = (const float*)d_in[5];
  const float* Dp      = (const float*)d_in[6];
  const float* norm_w  = (const float*)d_in[7];
  const float* W_out   = (const float*)d_in[8];

  char* ws = (char*)d_ws;
  size_t off = 0;
  auto nxt = [&](size_t bytes) -> char* {
    char* r = ws + off;
    off += (bytes + 255) & ~(size_t)255;
    return r;
  };
  char* RZ = nxt(4096ull * 4096 * 2);   // zbuf -> wout_bf
  char* RX = nxt(4096ull * 4352 * 2);   // xbc -> states(f32) -> ybuf
  char* RC = nxt(4096ull * 4352 * 2);   // win_bf -> xc -> ynbuf
  char* RH = nxt(1024ull * 8192 * 2);   // u_bf -> hprev
  float* dtw  = (float*)nxt(4096ull * 64 * 4);
  float* cdec = (float*)nxt(1024ull * 4);
  size_t need = off;
  (void)in_sizes; (void)n_in; (void)out_size;
  if (ws_size < need) return;

  unsigned short* zbuf    = (unsigned short*)RZ;
  unsigned short* wout_bf = (unsigned short*)RZ;   // after k_norm
  unsigned short* xbc     = (unsigned short*)RX;
  float*          states  = (float*)RX;
  unsigned short* ybuf    = (unsigned short*)RX;
  unsigned short* win_bf  = (unsigned short*)RC;
  unsigned short* xc      = (unsigned short*)RC;
  unsigned short* ynbuf   = (unsigned short*)RC;
  unsigned short* u_bf    = (unsigned short*)RH;
  unsigned short* hprev   = (unsigned short*)RH;

  k_f2bf<<<8192,  256, 0, stream>>>(u,    u_bf,   4096 * 2048);
  k_f2bf<<<17024, 256, 0, stream>>>(W_in, win_bf, 8512 * 2048);
  k_dtg<<<32, 256, 0, stream>>>(u_bf, win_bf, dt_bias, dtw);
  // in-proj: M=4096, N=8448 (dt cols excluded), K=2048; 256x256 tiles, grid 33x16
  k_gcnt<256,1><<<dim3(33, 16), 512, 0, stream>>>(u_bf, win_bf, zbuf, xbc, 8448, 2048);
  k_conv<<<8704, 256, 0, stream>>>(xbc, conv_w, conv_b, xc);
  k_states<<<1024, 256, 0, stream>>>(xc, dtw, A_log, states, cdec);
  k_scan<<<512, 256, 0, stream>>>(states, cdec, hprev);
  k_y<<<1024, 256, 0, stream>>>(xc, dtw, A_log, hprev, Dp, ybuf);
  k_norm<<<4096, 256, 0, stream>>>(ybuf, zbuf, norm_w, ynbuf);
  k_f2bf<<<8192, 256, 0, stream>>>(W_out, wout_bf, 2048 * 4096);
  // out-proj: M=4096, N=2048, K=4096; 128x256 tiles, grid 8x32 (256 blocks)
  k_gcnt<128,0><<<dim3(8, 32), 512, 0, stream>>>(ynbuf, wout_bf, d_out, nullptr, 2048, 4096);
}